// Round 1
// baseline (3473.159 us; speedup 1.0000x reference)
//
#include <hip/hip_runtime.h>
#include <cstddef>
#include <cstdint>
#include <math.h>

// Problem constants
#define LSEQ   4096
#define BATCH  4
#define TTOK   (LSEQ * BATCH)      // 16384 rows
// D_MODEL=512, D_INNER=1024, CONV_DIM=1152, NHEADS=16, HEADDIM=64, D_STATE=64
// raw buffer holds in_proj cols [1024,2192): 1152 xBC + 16 dt_raw -> ld 1168

// ---------------------------------------------------------------------------
// Generic fp32 GEMM: C[M,N] = act(A[M,K] @ W[N,K]^T + bias)
// 128x128 tile, BK=8, 256 threads, 8x8 microtile. M must be multiple of 128.
// ---------------------------------------------------------------------------
template<int ACT>   // 0 = none, 1 = silu
__global__ __launch_bounds__(256)
void gemm_tn(const float* __restrict__ A, const float* __restrict__ W,
             const float* __restrict__ bias, float* __restrict__ C,
             int M, int N, int K)
{
    __shared__ float As[8][128];
    __shared__ float Bs[8][128];
    const int tid = threadIdx.x;
    const int m0 = blockIdx.y * 128;
    const int n0 = blockIdx.x * 128;
    const int tx = tid & 15, ty = tid >> 4;
    const int lr = tid >> 1;           // 0..127
    const int lk = (tid & 1) * 4;      // 0 or 4

    const float* Ap = A + (size_t)(m0 + lr) * K + lk;
    const int wrow = n0 + lr;
    const float* Wp = W + (size_t)wrow * K + lk;
    const bool wv = wrow < N;

    float acc[8][8];
#pragma unroll
    for (int i = 0; i < 8; ++i)
#pragma unroll
        for (int j = 0; j < 8; ++j) acc[i][j] = 0.f;

    for (int k0 = 0; k0 < K; k0 += 8) {
        float4 av = *(const float4*)(Ap + k0);
        float4 wvv = wv ? *(const float4*)(Wp + k0) : make_float4(0.f, 0.f, 0.f, 0.f);
        __syncthreads();
        As[lk + 0][lr] = av.x;  As[lk + 1][lr] = av.y;
        As[lk + 2][lr] = av.z;  As[lk + 3][lr] = av.w;
        Bs[lk + 0][lr] = wvv.x; Bs[lk + 1][lr] = wvv.y;
        Bs[lk + 2][lr] = wvv.z; Bs[lk + 3][lr] = wvv.w;
        __syncthreads();
#pragma unroll
        for (int k = 0; k < 8; ++k) {
            float4 a0 = *(const float4*)&As[k][ty * 8];
            float4 a1 = *(const float4*)&As[k][ty * 8 + 4];
            float4 b0 = *(const float4*)&Bs[k][tx * 8];
            float4 b1 = *(const float4*)&Bs[k][tx * 8 + 4];
            float a[8] = {a0.x, a0.y, a0.z, a0.w, a1.x, a1.y, a1.z, a1.w};
            float b[8] = {b0.x, b0.y, b0.z, b0.w, b1.x, b1.y, b1.z, b1.w};
#pragma unroll
            for (int i = 0; i < 8; ++i)
#pragma unroll
                for (int j = 0; j < 8; ++j)
                    acc[i][j] = fmaf(a[i], b[j], acc[i][j]);
        }
    }

#pragma unroll
    for (int i = 0; i < 8; ++i) {
        const int row = m0 + ty * 8 + i;
#pragma unroll
        for (int j = 0; j < 8; ++j) {
            const int col = n0 + tx * 8 + j;
            if (col < N) {
                float v = acc[i][j];
                if (bias) v += bias[col];
                if (ACT == 1) v = v / (1.f + __expf(-v));   // silu
                C[(size_t)row * N + col] = v;
            }
        }
    }
}

// ---------------------------------------------------------------------------
// dt = softplus(raw_dt + dt_bias);  dA = exp(dt * (-exp(A_log)))
// ---------------------------------------------------------------------------
__global__ __launch_bounds__(256)
void dt_kernel(const float* __restrict__ raw, const float* __restrict__ dt_bias,
               const float* __restrict__ A_log, float* __restrict__ dt,
               float* __restrict__ dA, int n)
{
    int i = blockIdx.x * 256 + threadIdx.x;
    if (i >= n) return;
    int hh = i & 15;
    int row = i >> 4;
    float v = raw[(size_t)row * 1168 + 1152 + hh] + dt_bias[hh];
    float s = (v > 20.f) ? v : log1pf(expf(v));
    float Ah = -expf(A_log[hh]);
    dt[i] = s;
    dA[i] = expf(s * Ah);
}

// ---------------------------------------------------------------------------
// Anti-causal depthwise conv (time-reversed causal conv) + silu
// out[b,l,c] = silu(conv_b[c] + sum_k conv_w[c,k] * in[b, l+3-k, c])
// ---------------------------------------------------------------------------
__global__ __launch_bounds__(64)
void conv_silu(const float* __restrict__ raw, const float* __restrict__ cw,
               const float* __restrict__ cb, float* __restrict__ out)
{
    const int c = blockIdx.x * 64 + threadIdx.x;   // 0..1151
    const int row = blockIdx.y;                    // b*LSEQ + l
    const int l = row & (LSEQ - 1);
    float acc = cb[c];
#pragma unroll
    for (int k = 0; k < 4; ++k) {
        int ll = l + 3 - k;
        if (ll < LSEQ)
            acc = fmaf(cw[c * 4 + k], raw[(size_t)(row + 3 - k) * 1168 + c], acc);
    }
    acc = acc / (1.f + __expf(-acc));
    out[(size_t)row * 1152 + c] = acc;
}

// ---------------------------------------------------------------------------
// SSM scan, reversed time (l = LSEQ-1 .. 0).
// grid (4 p-quarters, 16 heads, 4 batch), 64 lanes.
// lane owns p = pq*16 + (lane&15), n in [(lane>>4)*16, +16)  -> 16 state regs
// y[p] = sum_n h[p,n]*C[n]  reduced across the 4 lane-groups via shfl_xor.
// ---------------------------------------------------------------------------
struct StepData {
    float4 B0, B1, B2, B3, C0, C1, C2, C3;
    float xh, dtv, dAv;
};

__global__ __launch_bounds__(64)
void scan_kernel(const float* __restrict__ xbc, const float* __restrict__ dtp,
                 const float* __restrict__ dAp, const float* __restrict__ Dvec,
                 float* __restrict__ y)
{
    const int pq = blockIdx.x, h = blockIdx.y, b = blockIdx.z;
    const int lane = threadIdx.x;
    const int p = pq * 16 + (lane & 15);
    const int ng = lane >> 4;
    const float Dh = Dvec[h];
    const size_t rb = (size_t)b * LSEQ;
    const float* xr = xbc + rb * 1152;
    const float* dtr = dtp + rb * 16 + h;
    const float* dAr = dAp + rb * 16 + h;
    float* yr = y + rb * 1024 + h * 64 + p;
    const int xhcol = h * 64 + p;
    const int bcol = 1024 + ng * 16;
    const int ccol = 1088 + ng * 16;

    float hs[16];
#pragma unroll
    for (int j = 0; j < 16; ++j) hs[j] = 0.f;

    auto ld = [&](int t, StepData& s) {
        const float* r = xr + (size_t)t * 1152;
        s.xh = r[xhcol];
        s.B0 = *(const float4*)(r + bcol);
        s.B1 = *(const float4*)(r + bcol + 4);
        s.B2 = *(const float4*)(r + bcol + 8);
        s.B3 = *(const float4*)(r + bcol + 12);
        s.C0 = *(const float4*)(r + ccol);
        s.C1 = *(const float4*)(r + ccol + 4);
        s.C2 = *(const float4*)(r + ccol + 8);
        s.C3 = *(const float4*)(r + ccol + 12);
        s.dtv = dtr[(size_t)t * 16];
        s.dAv = dAr[(size_t)t * 16];
    };

    StepData cur, nxt;
    ld(LSEQ - 1, cur);
    nxt = cur;
    for (int t = LSEQ - 1; t >= 0; --t) {
        if (t > 0) ld(t - 1, nxt);
        const float dtx = cur.dtv * cur.xh;
        const float dAv = cur.dAv;
        float acc = 0.f;
        const float Bv[16] = {cur.B0.x, cur.B0.y, cur.B0.z, cur.B0.w,
                              cur.B1.x, cur.B1.y, cur.B1.z, cur.B1.w,
                              cur.B2.x, cur.B2.y, cur.B2.z, cur.B2.w,
                              cur.B3.x, cur.B3.y, cur.B3.z, cur.B3.w};
        const float Cv[16] = {cur.C0.x, cur.C0.y, cur.C0.z, cur.C0.w,
                              cur.C1.x, cur.C1.y, cur.C1.z, cur.C1.w,
                              cur.C2.x, cur.C2.y, cur.C2.z, cur.C2.w,
                              cur.C3.x, cur.C3.y, cur.C3.z, cur.C3.w};
#pragma unroll
        for (int j = 0; j < 16; ++j) {
            hs[j] = fmaf(hs[j], dAv, dtx * Bv[j]);
            acc = fmaf(hs[j], Cv[j], acc);
        }
        acc += __shfl_xor(acc, 16);
        acc += __shfl_xor(acc, 32);
        if (ng == 0) yr[(size_t)t * 1024] = fmaf(Dh, cur.xh, acc);
        cur = nxt;
    }
}

// ---------------------------------------------------------------------------
// gated = y * silu(z); RMS-norm over 1024; * rms_w
// ---------------------------------------------------------------------------
__global__ __launch_bounds__(256)
void gate_rms(const float* __restrict__ y, const float* __restrict__ z,
              const float* __restrict__ rw, float* __restrict__ out)
{
    const int row = blockIdx.x;
    const int tid = threadIdx.x;
    float g[4];
    float ss = 0.f;
#pragma unroll
    for (int i = 0; i < 4; ++i) {
        int c = i * 256 + tid;
        float zv = z[(size_t)row * 1024 + c];
        float yv = y[(size_t)row * 1024 + c];
        float gv = yv * zv / (1.f + __expf(-zv));
        g[i] = gv;
        ss += gv * gv;
    }
#pragma unroll
    for (int off = 32; off > 0; off >>= 1) ss += __shfl_xor(ss, off);
    __shared__ float red[4];
    if ((tid & 63) == 0) red[tid >> 6] = ss;
    __syncthreads();
    ss = red[0] + red[1] + red[2] + red[3];
    const float inv = rsqrtf(ss * (1.f / 1024.f) + 1e-5f);
#pragma unroll
    for (int i = 0; i < 4; ++i) {
        int c = i * 256 + tid;
        out[(size_t)row * 1024 + c] = g[i] * inv * rw[c];
    }
}

// ---------------------------------------------------------------------------
// LayerNorm over 512
// ---------------------------------------------------------------------------
__global__ __launch_bounds__(256)
void layernorm_k(const float* __restrict__ x, const float* __restrict__ gg,
                 const float* __restrict__ bb, float* __restrict__ out)
{
    const int row = blockIdx.x;
    const int tid = threadIdx.x;
    float x0 = x[(size_t)row * 512 + tid];
    float x1 = x[(size_t)row * 512 + 256 + tid];
    float s = x0 + x1, ss = x0 * x0 + x1 * x1;
#pragma unroll
    for (int off = 32; off > 0; off >>= 1) {
        s += __shfl_xor(s, off);
        ss += __shfl_xor(ss, off);
    }
    __shared__ float rs[4], rss[4];
    if ((tid & 63) == 0) { rs[tid >> 6] = s; rss[tid >> 6] = ss; }
    __syncthreads();
    s = rs[0] + rs[1] + rs[2] + rs[3];
    ss = rss[0] + rss[1] + rss[2] + rss[3];
    const float mean = s * (1.f / 512.f);
    const float var = ss * (1.f / 512.f) - mean * mean;
    const float inv = rsqrtf(var + 1e-5f);
    out[(size_t)row * 512 + tid]       = (x0 - mean) * inv * gg[tid] + bb[tid];
    out[(size_t)row * 512 + 256 + tid] = (x1 - mean) * inv * gg[256 + tid] + bb[256 + tid];
}

// w1eff[j,d] = w1[j,d] + w1[j,512+d]   (folds cat([y,y]) @ w1^T)
__global__ __launch_bounds__(256)
void w1eff_k(const float* __restrict__ w1, float* __restrict__ we, int n)
{
    int i = blockIdx.x * 256 + threadIdx.x;
    if (i >= n) return;
    int j = i >> 9, d = i & 511;
    we[i] = w1[(size_t)j * 1024 + d] + w1[(size_t)j * 1024 + 512 + d];
}

// ---------------------------------------------------------------------------
extern "C" void kernel_launch(void* const* d_in, const int* in_sizes, int n_in,
                              void* d_out, int out_size, void* d_ws, size_t ws_size,
                              hipStream_t stream)
{
    const float* x         = (const float*)d_in[0];
    const float* in_proj_w = (const float*)d_in[1];   // (2192, 512)
    const float* conv_w    = (const float*)d_in[2];   // (1152, 4)
    const float* conv_b    = (const float*)d_in[3];
    const float* dt_bias   = (const float*)d_in[4];   // (16,)
    const float* A_log     = (const float*)d_in[5];
    const float* Dv        = (const float*)d_in[6];
    const float* rms_w     = (const float*)d_in[7];
    const float* out_proj_w= (const float*)d_in[8];   // (512, 1024)
    const float* ln_g      = (const float*)d_in[9];
    const float* ln_b      = (const float*)d_in[10];
    const float* w1        = (const float*)d_in[11];  // (1024, 1024)
    const float* b1        = (const float*)d_in[12];
    const float* w2        = (const float*)d_in[13];  // (512, 1024)
    const float* b2        = (const float*)d_in[14];
    float* out = (float*)d_out;
    float* ws  = (float*)d_ws;

    const size_t Tt = TTOK;
    // workspace layout (floats), with liveness-safe reuse:
    float* zbuf = ws;                         // [T,1024]  z
    float* raw  = ws + Tt * 1024;             // [T,1168]  xBC_raw | dt_raw
    float* xbcc = ws + Tt * 2192;             // [T,1152]  conv output
    float* dtb  = ws + Tt * 3344;             // [T,16]
    float* dab  = ws + Tt * 3360;             // [T,16]
    float* w1e  = ws + Tt * 3376;             // [1024,512]
    float* ysc  = raw;                        // scan out   [T,1024] (raw dead)
    float* vg   = xbcc;                       // gated+rms  [T,1024] (xbcc dead)
    float* y2   = ws;                         // out_proj   [T,512]  (zbuf dead)
    float* yln  = ws + Tt * 512;              // layernorm  [T,512]
    float* h1   = ws + Tt * 1024;             // mlp hidden [T,1024] (raw/ysc dead)

    // fold cat-weight (independent of activations)
    w1eff_k<<<(1024 * 512 + 255) / 256, 256, 0, stream>>>(w1, w1e, 1024 * 512);

    // in_proj, split into z and (xBC | dt_raw)
    gemm_tn<0><<<dim3(8, 128),  256, 0, stream>>>(x, in_proj_w, nullptr, zbuf, TTOK, 1024, 512);
    gemm_tn<0><<<dim3(10, 128), 256, 0, stream>>>(x, in_proj_w + (size_t)1024 * 512, nullptr, raw, TTOK, 1168, 512);

    dt_kernel<<<(TTOK * 16 + 255) / 256, 256, 0, stream>>>(raw, dt_bias, A_log, dtb, dab, TTOK * 16);
    conv_silu<<<dim3(18, TTOK), 64, 0, stream>>>(raw, conv_w, conv_b, xbcc);

    scan_kernel<<<dim3(4, 16, 4), 64, 0, stream>>>(xbcc, dtb, dab, Dv, ysc);

    gate_rms<<<TTOK, 256, 0, stream>>>(ysc, zbuf, rms_w, vg);
    gemm_tn<0><<<dim3(4, 128), 256, 0, stream>>>(vg, out_proj_w, nullptr, y2, TTOK, 512, 1024);
    layernorm_k<<<TTOK, 256, 0, stream>>>(y2, ln_g, ln_b, yln);

    gemm_tn<1><<<dim3(8, 128), 256, 0, stream>>>(yln, w1e, b1, h1, TTOK, 1024, 512);
    gemm_tn<0><<<dim3(4, 128), 256, 0, stream>>>(h1, w2, b2, out, TTOK, 512, 1024);
}

// Round 2
// 1996.829 us; speedup vs baseline: 1.7393x; 1.7393x over previous
//
#include <hip/hip_runtime.h>
#include <cstddef>
#include <cstdint>
#include <math.h>

// Problem constants
#define LSEQ   4096
#define BATCH  4
#define TTOK   (LSEQ * BATCH)      // 16384 rows
#define QCH    128                 // scan chunk length
#define NCH    (LSEQ / QCH)        // 32 chunks per sequence
// D_MODEL=512, D_INNER=1024, CONV_DIM=1152, NHEADS=16, HEADDIM=64, D_STATE=64
// raw buffer holds in_proj cols [1024,2192): 1152 xBC + 16 dt_raw -> ld 1168

// ---------------------------------------------------------------------------
// Generic fp32 GEMM: C[M,N] = act(A[M,K] @ W[N,K]^T + bias)
// 128x128 tile, BK=8, 256 threads, 8x8 microtile. M must be multiple of 128.
// ---------------------------------------------------------------------------
template<int ACT>   // 0 = none, 1 = silu
__global__ __launch_bounds__(256)
void gemm_tn(const float* __restrict__ A, const float* __restrict__ W,
             const float* __restrict__ bias, float* __restrict__ C,
             int M, int N, int K)
{
    __shared__ float As[8][128];
    __shared__ float Bs[8][128];
    const int tid = threadIdx.x;
    const int m0 = blockIdx.y * 128;
    const int n0 = blockIdx.x * 128;
    const int tx = tid & 15, ty = tid >> 4;
    const int lr = tid >> 1;           // 0..127
    const int lk = (tid & 1) * 4;      // 0 or 4

    const float* Ap = A + (size_t)(m0 + lr) * K + lk;
    const int wrow = n0 + lr;
    const float* Wp = W + (size_t)wrow * K + lk;
    const bool wv = wrow < N;

    float acc[8][8];
#pragma unroll
    for (int i = 0; i < 8; ++i)
#pragma unroll
        for (int j = 0; j < 8; ++j) acc[i][j] = 0.f;

    for (int k0 = 0; k0 < K; k0 += 8) {
        float4 av = *(const float4*)(Ap + k0);
        float4 wvv = wv ? *(const float4*)(Wp + k0) : make_float4(0.f, 0.f, 0.f, 0.f);
        __syncthreads();
        As[lk + 0][lr] = av.x;  As[lk + 1][lr] = av.y;
        As[lk + 2][lr] = av.z;  As[lk + 3][lr] = av.w;
        Bs[lk + 0][lr] = wvv.x; Bs[lk + 1][lr] = wvv.y;
        Bs[lk + 2][lr] = wvv.z; Bs[lk + 3][lr] = wvv.w;
        __syncthreads();
#pragma unroll
        for (int k = 0; k < 8; ++k) {
            float4 a0 = *(const float4*)&As[k][ty * 8];
            float4 a1 = *(const float4*)&As[k][ty * 8 + 4];
            float4 b0 = *(const float4*)&Bs[k][tx * 8];
            float4 b1 = *(const float4*)&Bs[k][tx * 8 + 4];
            float a[8] = {a0.x, a0.y, a0.z, a0.w, a1.x, a1.y, a1.z, a1.w};
            float b[8] = {b0.x, b0.y, b0.z, b0.w, b1.x, b1.y, b1.z, b1.w};
#pragma unroll
            for (int i = 0; i < 8; ++i)
#pragma unroll
                for (int j = 0; j < 8; ++j)
                    acc[i][j] = fmaf(a[i], b[j], acc[i][j]);
        }
    }

#pragma unroll
    for (int i = 0; i < 8; ++i) {
        const int row = m0 + ty * 8 + i;
#pragma unroll
        for (int j = 0; j < 8; ++j) {
            const int col = n0 + tx * 8 + j;
            if (col < N) {
                float v = acc[i][j];
                if (bias) v += bias[col];
                if (ACT == 1) v = v / (1.f + __expf(-v));   // silu
                C[(size_t)row * N + col] = v;
            }
        }
    }
}

// ---------------------------------------------------------------------------
// dt = softplus(raw_dt + dt_bias);  dA = exp(dt * (-exp(A_log)))
// ---------------------------------------------------------------------------
__global__ __launch_bounds__(256)
void dt_kernel(const float* __restrict__ raw, const float* __restrict__ dt_bias,
               const float* __restrict__ A_log, float* __restrict__ dt,
               float* __restrict__ dA, int n)
{
    int i = blockIdx.x * 256 + threadIdx.x;
    if (i >= n) return;
    int hh = i & 15;
    int row = i >> 4;
    float v = raw[(size_t)row * 1168 + 1152 + hh] + dt_bias[hh];
    float s = (v > 20.f) ? v : log1pf(expf(v));
    float Ah = -expf(A_log[hh]);
    dt[i] = s;
    dA[i] = expf(s * Ah);
}

// ---------------------------------------------------------------------------
// Anti-causal depthwise conv (time-reversed causal conv) + silu
// ---------------------------------------------------------------------------
__global__ __launch_bounds__(64)
void conv_silu(const float* __restrict__ raw, const float* __restrict__ cw,
               const float* __restrict__ cb, float* __restrict__ out)
{
    const int c = blockIdx.x * 64 + threadIdx.x;   // 0..1151
    const int row = blockIdx.y;                    // b*LSEQ + l
    const int l = row & (LSEQ - 1);
    float acc = cb[c];
#pragma unroll
    for (int k = 0; k < 4; ++k) {
        int ll = l + 3 - k;
        if (ll < LSEQ)
            acc = fmaf(cw[c * 4 + k], raw[(size_t)(row + 3 - k) * 1168 + c], acc);
    }
    acc = acc / (1.f + __expf(-acc));
    out[(size_t)row * 1152 + c] = acc;
}

// ---------------------------------------------------------------------------
// Chunked SSM scan, reversed time. The linear recurrence
//   h[t] = dA[t] h[t+1-direction...]  (we scan t = L-1 .. 0)
// is split into NCH chunks of QCH steps:
//   pass 1 (scan_local):  per-chunk scan from h=0; store end state + P=prod dA
//   pass 2 (scan_combine): tiny sequential scan across chunks -> h_start[c]
//   pass 3 (scan_final):  per-chunk scan seeded with h_start, writes y
// Lane layout (64 lanes): p = pq*16 + (lane&15), n in [ (lane>>4)*16, +16 )
// ---------------------------------------------------------------------------
struct StepB {
    float4 B0, B1, B2, B3;
    float xh, dtv, dAv;
};

__device__ __forceinline__ void load_stepB(const float* __restrict__ r,
                                           const float* __restrict__ dtr,
                                           const float* __restrict__ dAr,
                                           int t, int xhcol, int bcol, StepB& s)
{
    const float* rr = r + (size_t)t * 1152;
    s.xh = rr[xhcol];
    s.B0 = *(const float4*)(rr + bcol);
    s.B1 = *(const float4*)(rr + bcol + 4);
    s.B2 = *(const float4*)(rr + bcol + 8);
    s.B3 = *(const float4*)(rr + bcol + 12);
    s.dtv = dtr[(size_t)t * 16];
    s.dAv = dAr[(size_t)t * 16];
}

__global__ __launch_bounds__(64)
void scan_local(const float* __restrict__ xbc, const float* __restrict__ dtp,
                const float* __restrict__ dAp, float* __restrict__ sbuf,
                float* __restrict__ Pbuf)
{
    const int pq = blockIdx.x & 3, c = blockIdx.x >> 2;
    const int h = blockIdx.y, b = blockIdx.z;
    const int lane = threadIdx.x;
    const int p = pq * 16 + (lane & 15);
    const int ng = lane >> 4;
    const size_t rb = (size_t)b * LSEQ;
    const float* xr = xbc + rb * 1152;
    const float* dtr = dtp + rb * 16 + h;
    const float* dAr = dAp + rb * 16 + h;
    const int xhcol = h * 64 + p;
    const int bcol = 1024 + ng * 16;
    const int t_lo = c * QCH, t_hi = c * QCH + QCH - 1;

    float hs[16];
#pragma unroll
    for (int j = 0; j < 16; ++j) hs[j] = 0.f;
    float Pp = 1.f;

    StepB cur, nxt;
    load_stepB(xr, dtr, dAr, t_hi, xhcol, bcol, cur);
    nxt = cur;
    for (int t = t_hi; t >= t_lo; --t) {
        if (t > t_lo) load_stepB(xr, dtr, dAr, t - 1, xhcol, bcol, nxt);
        const float dtx = cur.dtv * cur.xh;
        const float dAv = cur.dAv;
        Pp *= dAv;
        const float Bv[16] = {cur.B0.x, cur.B0.y, cur.B0.z, cur.B0.w,
                              cur.B1.x, cur.B1.y, cur.B1.z, cur.B1.w,
                              cur.B2.x, cur.B2.y, cur.B2.z, cur.B2.w,
                              cur.B3.x, cur.B3.y, cur.B3.z, cur.B3.w};
#pragma unroll
        for (int j = 0; j < 16; ++j)
            hs[j] = fmaf(hs[j], dAv, dtx * Bv[j]);
        cur = nxt;
    }

    float* sp = sbuf + (((size_t)(b * 16 + h) * NCH + c) * 4096) + p * 64 + ng * 16;
    *(float4*)(sp + 0)  = make_float4(hs[0],  hs[1],  hs[2],  hs[3]);
    *(float4*)(sp + 4)  = make_float4(hs[4],  hs[5],  hs[6],  hs[7]);
    *(float4*)(sp + 8)  = make_float4(hs[8],  hs[9],  hs[10], hs[11]);
    *(float4*)(sp + 12) = make_float4(hs[12], hs[13], hs[14], hs[15]);
    if (pq == 0 && lane == 0) Pbuf[(b * 16 + h) * NCH + c] = Pp;
}

__global__ __launch_bounds__(64)
void scan_combine(float* __restrict__ sbuf, const float* __restrict__ Pbuf)
{
    const int pq = blockIdx.x, h = blockIdx.y, b = blockIdx.z;
    const int lane = threadIdx.x;
    const int p = pq * 16 + (lane & 15);
    const int ng = lane >> 4;
    const size_t base = (size_t)(b * 16 + h) * NCH;

    float carry[16];
#pragma unroll
    for (int j = 0; j < 16; ++j) carry[j] = 0.f;

    auto sp_at = [&](int c) {
        return sbuf + (base + c) * 4096 + p * 64 + ng * 16;
    };

    float4 L0 = *(const float4*)(sp_at(NCH - 1) + 0);
    float4 L1 = *(const float4*)(sp_at(NCH - 1) + 4);
    float4 L2 = *(const float4*)(sp_at(NCH - 1) + 8);
    float4 L3 = *(const float4*)(sp_at(NCH - 1) + 12);
    float Pn = Pbuf[base + NCH - 1];

    for (int c = NCH - 1; c >= 0; --c) {
        float lv[16] = {L0.x, L0.y, L0.z, L0.w, L1.x, L1.y, L1.z, L1.w,
                        L2.x, L2.y, L2.z, L2.w, L3.x, L3.y, L3.z, L3.w};
        float Pc = Pn;
        if (c > 0) {
            float* spn = sp_at(c - 1);
            L0 = *(const float4*)(spn + 0);
            L1 = *(const float4*)(spn + 4);
            L2 = *(const float4*)(spn + 8);
            L3 = *(const float4*)(spn + 12);
            Pn = Pbuf[base + c - 1];
        }
        float* sp = sp_at(c);
        // overwrite local-end with h_start for this chunk
        *(float4*)(sp + 0)  = make_float4(carry[0],  carry[1],  carry[2],  carry[3]);
        *(float4*)(sp + 4)  = make_float4(carry[4],  carry[5],  carry[6],  carry[7]);
        *(float4*)(sp + 8)  = make_float4(carry[8],  carry[9],  carry[10], carry[11]);
        *(float4*)(sp + 12) = make_float4(carry[12], carry[13], carry[14], carry[15]);
#pragma unroll
        for (int j = 0; j < 16; ++j)
            carry[j] = fmaf(carry[j], Pc, lv[j]);
    }
}

struct StepBC {
    float4 B0, B1, B2, B3, C0, C1, C2, C3;
    float xh, dtv, dAv;
};

__global__ __launch_bounds__(64)
void scan_final(const float* __restrict__ xbc, const float* __restrict__ dtp,
                const float* __restrict__ dAp, const float* __restrict__ Dvec,
                const float* __restrict__ sbuf, float* __restrict__ y)
{
    const int pq = blockIdx.x & 3, c = blockIdx.x >> 2;
    const int h = blockIdx.y, b = blockIdx.z;
    const int lane = threadIdx.x;
    const int p = pq * 16 + (lane & 15);
    const int ng = lane >> 4;
    const float Dh = Dvec[h];
    const size_t rb = (size_t)b * LSEQ;
    const float* xr = xbc + rb * 1152;
    const float* dtr = dtp + rb * 16 + h;
    const float* dAr = dAp + rb * 16 + h;
    float* yr = y + rb * 1024 + h * 64 + p;
    const int xhcol = h * 64 + p;
    const int bcol = 1024 + ng * 16;
    const int ccol = 1088 + ng * 16;
    const int t_lo = c * QCH, t_hi = c * QCH + QCH - 1;

    // seed from h_start
    const float* sp = sbuf + (((size_t)(b * 16 + h) * NCH + c) * 4096) + p * 64 + ng * 16;
    float4 H0 = *(const float4*)(sp + 0);
    float4 H1 = *(const float4*)(sp + 4);
    float4 H2 = *(const float4*)(sp + 8);
    float4 H3 = *(const float4*)(sp + 12);
    float hs[16] = {H0.x, H0.y, H0.z, H0.w, H1.x, H1.y, H1.z, H1.w,
                    H2.x, H2.y, H2.z, H2.w, H3.x, H3.y, H3.z, H3.w};

    auto ld = [&](int t, StepBC& s) {
        const float* r = xr + (size_t)t * 1152;
        s.xh = r[xhcol];
        s.B0 = *(const float4*)(r + bcol);
        s.B1 = *(const float4*)(r + bcol + 4);
        s.B2 = *(const float4*)(r + bcol + 8);
        s.B3 = *(const float4*)(r + bcol + 12);
        s.C0 = *(const float4*)(r + ccol);
        s.C1 = *(const float4*)(r + ccol + 4);
        s.C2 = *(const float4*)(r + ccol + 8);
        s.C3 = *(const float4*)(r + ccol + 12);
        s.dtv = dtr[(size_t)t * 16];
        s.dAv = dAr[(size_t)t * 16];
    };

    StepBC cur, nxt;
    ld(t_hi, cur);
    nxt = cur;
    for (int t = t_hi; t >= t_lo; --t) {
        if (t > t_lo) ld(t - 1, nxt);
        const float dtx = cur.dtv * cur.xh;
        const float dAv = cur.dAv;
        float acc = 0.f;
        const float Bv[16] = {cur.B0.x, cur.B0.y, cur.B0.z, cur.B0.w,
                              cur.B1.x, cur.B1.y, cur.B1.z, cur.B1.w,
                              cur.B2.x, cur.B2.y, cur.B2.z, cur.B2.w,
                              cur.B3.x, cur.B3.y, cur.B3.z, cur.B3.w};
        const float Cv[16] = {cur.C0.x, cur.C0.y, cur.C0.z, cur.C0.w,
                              cur.C1.x, cur.C1.y, cur.C1.z, cur.C1.w,
                              cur.C2.x, cur.C2.y, cur.C2.z, cur.C2.w,
                              cur.C3.x, cur.C3.y, cur.C3.z, cur.C3.w};
#pragma unroll
        for (int j = 0; j < 16; ++j) {
            hs[j] = fmaf(hs[j], dAv, dtx * Bv[j]);
            acc = fmaf(hs[j], Cv[j], acc);
        }
        acc += __shfl_xor(acc, 16);
        acc += __shfl_xor(acc, 32);
        if (ng == 0) yr[(size_t)t * 1024] = fmaf(Dh, cur.xh, acc);
        cur = nxt;
    }
}

// ---------------------------------------------------------------------------
// gated = y * silu(z); RMS-norm over 1024; * rms_w
// ---------------------------------------------------------------------------
__global__ __launch_bounds__(256)
void gate_rms(const float* __restrict__ y, const float* __restrict__ z,
              const float* __restrict__ rw, float* __restrict__ out)
{
    const int row = blockIdx.x;
    const int tid = threadIdx.x;
    float g[4];
    float ss = 0.f;
#pragma unroll
    for (int i = 0; i < 4; ++i) {
        int c = i * 256 + tid;
        float zv = z[(size_t)row * 1024 + c];
        float yv = y[(size_t)row * 1024 + c];
        float gv = yv * zv / (1.f + __expf(-zv));
        g[i] = gv;
        ss += gv * gv;
    }
#pragma unroll
    for (int off = 32; off > 0; off >>= 1) ss += __shfl_xor(ss, off);
    __shared__ float red[4];
    if ((tid & 63) == 0) red[tid >> 6] = ss;
    __syncthreads();
    ss = red[0] + red[1] + red[2] + red[3];
    const float inv = rsqrtf(ss * (1.f / 1024.f) + 1e-5f);
#pragma unroll
    for (int i = 0; i < 4; ++i) {
        int c = i * 256 + tid;
        out[(size_t)row * 1024 + c] = g[i] * inv * rw[c];
    }
}

// ---------------------------------------------------------------------------
// LayerNorm over 512
// ---------------------------------------------------------------------------
__global__ __launch_bounds__(256)
void layernorm_k(const float* __restrict__ x, const float* __restrict__ gg,
                 const float* __restrict__ bb, float* __restrict__ out)
{
    const int row = blockIdx.x;
    const int tid = threadIdx.x;
    float x0 = x[(size_t)row * 512 + tid];
    float x1 = x[(size_t)row * 512 + 256 + tid];
    float s = x0 + x1, ss = x0 * x0 + x1 * x1;
#pragma unroll
    for (int off = 32; off > 0; off >>= 1) {
        s += __shfl_xor(s, off);
        ss += __shfl_xor(ss, off);
    }
    __shared__ float rs[4], rss[4];
    if ((tid & 63) == 0) { rs[tid >> 6] = s; rss[tid >> 6] = ss; }
    __syncthreads();
    s = rs[0] + rs[1] + rs[2] + rs[3];
    ss = rss[0] + rss[1] + rss[2] + rss[3];
    const float mean = s * (1.f / 512.f);
    const float var = ss * (1.f / 512.f) - mean * mean;
    const float inv = rsqrtf(var + 1e-5f);
    out[(size_t)row * 512 + tid]       = (x0 - mean) * inv * gg[tid] + bb[tid];
    out[(size_t)row * 512 + 256 + tid] = (x1 - mean) * inv * gg[256 + tid] + bb[256 + tid];
}

// w1eff[j,d] = w1[j,d] + w1[j,512+d]   (folds cat([y,y]) @ w1^T)
__global__ __launch_bounds__(256)
void w1eff_k(const float* __restrict__ w1, float* __restrict__ we, int n)
{
    int i = blockIdx.x * 256 + threadIdx.x;
    if (i >= n) return;
    int j = i >> 9, d = i & 511;
    we[i] = w1[(size_t)j * 1024 + d] + w1[(size_t)j * 1024 + 512 + d];
}

// ---------------------------------------------------------------------------
extern "C" void kernel_launch(void* const* d_in, const int* in_sizes, int n_in,
                              void* d_out, int out_size, void* d_ws, size_t ws_size,
                              hipStream_t stream)
{
    const float* x         = (const float*)d_in[0];
    const float* in_proj_w = (const float*)d_in[1];   // (2192, 512)
    const float* conv_w    = (const float*)d_in[2];   // (1152, 4)
    const float* conv_b    = (const float*)d_in[3];
    const float* dt_bias   = (const float*)d_in[4];   // (16,)
    const float* A_log     = (const float*)d_in[5];
    const float* Dv        = (const float*)d_in[6];
    const float* rms_w     = (const float*)d_in[7];
    const float* out_proj_w= (const float*)d_in[8];   // (512, 1024)
    const float* ln_g      = (const float*)d_in[9];
    const float* ln_b      = (const float*)d_in[10];
    const float* w1        = (const float*)d_in[11];  // (1024, 1024)
    const float* b1        = (const float*)d_in[12];
    const float* w2        = (const float*)d_in[13];  // (512, 1024)
    const float* b2        = (const float*)d_in[14];
    float* out = (float*)d_out;
    float* ws  = (float*)d_ws;

    const size_t Tt = TTOK;
    // workspace layout (floats), with liveness-safe reuse:
    float* zbuf = ws;                         // [T,1024]  z
    float* raw  = ws + Tt * 1024;             // [T,1168]  xBC_raw | dt_raw
    float* xbcc = ws + Tt * 2192;             // [T,1152]  conv output
    float* dtb  = ws + Tt * 3344;             // [T,16]
    float* dab  = ws + Tt * 3360;             // [T,16]
    float* w1e  = ws + Tt * 3376;             // [1024,512]
    float* Pbuf = ws + Tt * 3376 + 1024 * 512;// [4*16*NCH] chunk decay products
    float* ysc  = raw;                        // scan out   [T,1024] (raw dead)
    float* vg   = xbcc;                       // gated+rms  [T,1024] (xbcc dead)
    float* y2   = ws;                         // out_proj   [T,512]  (zbuf dead)
    float* yln  = ws + Tt * 512;              // layernorm  [T,512]
    float* h1   = ws + Tt * 1024;             // mlp hidden [T,1024] (raw/ysc dead)
    // chunk states: 4*16*NCH*4096 floats == TTOK*512 == out_size exactly.
    // d_out is dead until the final GEMM -> use it as the state buffer.
    float* sbuf = out;

    // fold cat-weight (independent of activations)
    w1eff_k<<<(1024 * 512 + 255) / 256, 256, 0, stream>>>(w1, w1e, 1024 * 512);

    // in_proj, split into z and (xBC | dt_raw)
    gemm_tn<0><<<dim3(8, 128),  256, 0, stream>>>(x, in_proj_w, nullptr, zbuf, TTOK, 1024, 512);
    gemm_tn<0><<<dim3(10, 128), 256, 0, stream>>>(x, in_proj_w + (size_t)1024 * 512, nullptr, raw, TTOK, 1168, 512);

    dt_kernel<<<(TTOK * 16 + 255) / 256, 256, 0, stream>>>(raw, dt_bias, A_log, dtb, dab, TTOK * 16);
    conv_silu<<<dim3(18, TTOK), 64, 0, stream>>>(raw, conv_w, conv_b, xbcc);

    // chunked scan: local -> combine -> final
    scan_local  <<<dim3(4 * NCH, 16, 4), 64, 0, stream>>>(xbcc, dtb, dab, sbuf, Pbuf);
    scan_combine<<<dim3(4, 16, 4),       64, 0, stream>>>(sbuf, Pbuf);
    scan_final  <<<dim3(4 * NCH, 16, 4), 64, 0, stream>>>(xbcc, dtb, dab, Dv, sbuf, ysc);

    gate_rms<<<TTOK, 256, 0, stream>>>(ysc, zbuf, rms_w, vg);
    gemm_tn<0><<<dim3(4, 128), 256, 0, stream>>>(vg, out_proj_w, nullptr, y2, TTOK, 512, 1024);
    layernorm_k<<<TTOK, 256, 0, stream>>>(y2, ln_g, ln_b, yln);

    gemm_tn<1><<<dim3(8, 128), 256, 0, stream>>>(yln, w1e, b1, h1, TTOK, 1024, 512);
    gemm_tn<0><<<dim3(4, 128), 256, 0, stream>>>(h1, w2, b2, out, TTOK, 512, 1024);
}

// Round 3
// 865.129 us; speedup vs baseline: 4.0146x; 2.3081x over previous
//
#include <hip/hip_runtime.h>
#include <cstddef>
#include <cstdint>
#include <math.h>

// Problem constants
#define LSEQ   4096
#define BATCH  4
#define TTOK   (LSEQ * BATCH)      // 16384 rows
#define QCH    128                 // scan chunk length
#define NCH    (LSEQ / QCH)        // 32 chunks per sequence
#define NPAD   2304                // in_proj N padded to 18*128
// D_MODEL=512, D_INNER=1024, CONV_DIM=1152, NHEADS=16, HEADDIM=64, D_STATE=64
// g1out layout (ld 2304): [0,1024) z | [1024,2176) xBC | [2176,2192) dt_raw | pad

typedef __attribute__((ext_vector_type(8))) short short8;
typedef __attribute__((ext_vector_type(4))) float floatx4;

// ---- bf16 helpers (manual, RNE) ----
__device__ __forceinline__ float bf2f(ushort u) {
    union { unsigned int i; float f; } v; v.i = ((unsigned int)u) << 16; return v.f;
}
__device__ __forceinline__ ushort f2bf(float f) {
    union { float f; unsigned int i; } v; v.f = f;
    unsigned int r = v.i + 0x7fffu + ((v.i >> 16) & 1u);
    return (ushort)(r >> 16);
}

__device__ __forceinline__ void storev(float* p, float v)  { *p = v; }
__device__ __forceinline__ void storev(ushort* p, float v) { *p = f2bf(v); }

// async 16B global -> LDS (wave-uniform LDS base + lane*16)
__device__ __forceinline__ void gload_lds16(const ushort* g, short* l) {
    __builtin_amdgcn_global_load_lds(
        (const __attribute__((address_space(1))) void*)g,
        (__attribute__((address_space(3))) void*)l, 16, 0, 0);
}

// ---------------------------------------------------------------------------
// bf16 MFMA GEMM: C[M,N] = act(A[M,K] @ W[N,K]^T + bias)
// 128x128 tile, BK=32, 256 threads = 4 waves, each wave does a 64x64 quadrant
// as 4x4 grid of 16x16x32 MFMAs. A,W bf16 (K-contiguous). M,N %128==0, K%32==0.
// LDS chunks XOR-swizzled (chunk q stored at slot q^(row&3)) to break the
// 8-way ds_read_b128 bank conflict down to ~2-way.
// ---------------------------------------------------------------------------
template<int ACT, typename OutT>   // ACT: 0 none, 1 silu
__global__ __launch_bounds__(256)
void gemm_mfma(const ushort* __restrict__ A, const ushort* __restrict__ W,
               const float* __restrict__ bias, OutT* __restrict__ C,
               int M, int N, int K)
{
    __shared__ __align__(16) short As[128 * 32];
    __shared__ __align__(16) short Ws[128 * 32];
    const int tid = threadIdx.x;
    const int w = tid >> 6, l = tid & 63;
    const int m0 = blockIdx.y * 128, n0 = blockIdx.x * 128;

    // staging: chunk ci = k*256 + tid; row = ci>>2, slot c = tid&3,
    // fetch global k-chunk q = c ^ (row&3)  (so read-side swizzle recovers it)
    const ushort* ga[2]; const ushort* gw[2];
    short* la[2]; short* lw[2];
#pragma unroll
    for (int k = 0; k < 2; ++k) {
        int row = (k * 256 + tid) >> 2;
        int c = tid & 3;
        int q = c ^ (row & 3);
        ga[k] = A + (size_t)(m0 + row) * K + q * 8;
        gw[k] = W + (size_t)(n0 + row) * K + q * 8;
        la[k] = As + (k * 64 + w * 16) * 32;   // wave-uniform base
        lw[k] = Ws + (k * 64 + w * 16) * 32;
    }

    const int lm = l & 15, quad = l >> 4;
    const int wm = w & 1, wn = w >> 1;
    int aoff[4], boff[4];
#pragma unroll
    for (int i = 0; i < 4; ++i) {
        int ra = wm * 64 + i * 16 + lm;
        aoff[i] = ra * 32 + ((quad ^ (ra & 3)) * 8);
        int rb = wn * 64 + i * 16 + lm;
        boff[i] = rb * 32 + ((quad ^ (rb & 3)) * 8);
    }

    floatx4 acc[4][4];
#pragma unroll
    for (int i = 0; i < 4; ++i)
#pragma unroll
        for (int j = 0; j < 4; ++j) acc[i][j] = (floatx4){0.f, 0.f, 0.f, 0.f};

    for (int k0 = 0; k0 < K; k0 += 32) {
#pragma unroll
        for (int k = 0; k < 2; ++k) {
            gload_lds16(ga[k] + k0, la[k]);
            gload_lds16(gw[k] + k0, lw[k]);
        }
        __syncthreads();   // drains vmcnt (global_load_lds) before reads
        short8 af[4], bfr[4];
#pragma unroll
        for (int i = 0; i < 4; ++i) af[i]  = *(const short8*)(As + aoff[i]);
#pragma unroll
        for (int j = 0; j < 4; ++j) bfr[j] = *(const short8*)(Ws + boff[j]);
#pragma unroll
        for (int i = 0; i < 4; ++i)
#pragma unroll
            for (int j = 0; j < 4; ++j)
                acc[i][j] = __builtin_amdgcn_mfma_f32_16x16x32_bf16(
                    af[i], bfr[j], acc[i][j], 0, 0, 0);
        __syncthreads();   // before next tile overwrites LDS
    }

    // epilogue: C/D layout col=lane&15, row=(lane>>4)*4+reg
#pragma unroll
    for (int i = 0; i < 4; ++i) {
        const int rbase = m0 + wm * 64 + i * 16 + quad * 4;
#pragma unroll
        for (int r = 0; r < 4; ++r) {
#pragma unroll
            for (int j = 0; j < 4; ++j) {
                const int col = n0 + wn * 64 + j * 16 + lm;
                float v = acc[i][j][r];
                if (bias) v += bias[col];
                if (ACT == 1) v = v / (1.f + __expf(-v));
                storev(&C[(size_t)(rbase + r) * N + col], v);
            }
        }
    }
}

// ---------------------------------------------------------------------------
// casts
// ---------------------------------------------------------------------------
__global__ __launch_bounds__(256)
void cast_x_k(const float4* __restrict__ in, ushort4* __restrict__ out, int n4)
{
    int i = blockIdx.x * 256 + threadIdx.x;
    if (i >= n4) return;
    float4 v = in[i];
    ushort4 o;
    o.x = f2bf(v.x); o.y = f2bf(v.y); o.z = f2bf(v.z); o.w = f2bf(v.w);
    out[i] = o;
}

__global__ __launch_bounds__(256)
void cast_inproj_k(const float* __restrict__ w, ushort* __restrict__ o)
{
    int i = blockIdx.x * 256 + threadIdx.x;   // over NPAD*512/4
    int i4 = i * 4;
    if (i4 >= NPAD * 512) return;
    int row = i4 >> 9;
    ushort4 v;
    if (row < 2192) {
        const float4 s = *(const float4*)(w + (size_t)i4);
        v.x = f2bf(s.x); v.y = f2bf(s.y); v.z = f2bf(s.z); v.w = f2bf(s.w);
    } else {
        v.x = v.y = v.z = v.w = 0;
    }
    *(ushort4*)(o + i4) = v;
}

// w1eff[j,d] = bf16(w1[j,d] + w1[j,512+d])
__global__ __launch_bounds__(256)
void w1eff_k(const float* __restrict__ w1, ushort* __restrict__ we)
{
    int i = blockIdx.x * 256 + threadIdx.x;   // over 1024*512/4
    int i4 = i * 4;
    if (i4 >= 1024 * 512) return;
    int j = i4 >> 9, d = i4 & 511;
    float4 a = *(const float4*)(w1 + (size_t)j * 1024 + d);
    float4 b = *(const float4*)(w1 + (size_t)j * 1024 + 512 + d);
    ushort4 v;
    v.x = f2bf(a.x + b.x); v.y = f2bf(a.y + b.y);
    v.z = f2bf(a.z + b.z); v.w = f2bf(a.w + b.w);
    *(ushort4*)(we + i4) = v;
}

// ---------------------------------------------------------------------------
// dt = softplus(raw_dt + dt_bias);  dA = exp(dt * (-exp(A_log)))
// ---------------------------------------------------------------------------
__global__ __launch_bounds__(256)
void dt_kernel(const ushort* __restrict__ raw, const float* __restrict__ dt_bias,
               const float* __restrict__ A_log, float* __restrict__ dt,
               float* __restrict__ dA, int n)
{
    int i = blockIdx.x * 256 + threadIdx.x;
    if (i >= n) return;
    int hh = i & 15;
    int row = i >> 4;
    float v = bf2f(raw[(size_t)row * NPAD + 2176 + hh]) + dt_bias[hh];
    float s = (v > 20.f) ? v : log1pf(expf(v));
    float Ah = -expf(A_log[hh]);
    dt[i] = s;
    dA[i] = expf(s * Ah);
}

// ---------------------------------------------------------------------------
// Anti-causal depthwise conv (time-reversed) + silu, bf16 in, fp32 out
// ---------------------------------------------------------------------------
__global__ __launch_bounds__(64)
void conv_silu(const ushort* __restrict__ raw, const float* __restrict__ cw,
               const float* __restrict__ cb, float* __restrict__ out)
{
    const int c = blockIdx.x * 64 + threadIdx.x;   // 0..1151
    const int row = blockIdx.y;                    // b*LSEQ + l
    const int l = row & (LSEQ - 1);
    float acc = cb[c];
#pragma unroll
    for (int k = 0; k < 4; ++k) {
        int ll = l + 3 - k;
        if (ll < LSEQ)
            acc = fmaf(cw[c * 4 + k], bf2f(raw[(size_t)(row + 3 - k) * NPAD + 1024 + c]), acc);
    }
    acc = acc / (1.f + __expf(-acc));
    out[(size_t)row * 1152 + c] = acc;
}

// ---------------------------------------------------------------------------
// Chunked SSM scan, reversed time (t = L-1 .. 0), 3 passes.
// Block = 256 threads = 4 waves; wave pq owns p in [pq*16, +16).
// Lane: p = pq*16 + (lane&15), n in [(lane>>4)*16, +16) -> 16 state regs.
// ---------------------------------------------------------------------------
__global__ __launch_bounds__(256)
void scan_local(const float* __restrict__ xbc, const float* __restrict__ dtp,
                const float* __restrict__ dAp, float* __restrict__ sbuf,
                float* __restrict__ Pbuf)
{
    const int tid = threadIdx.x;
    const int pq = tid >> 6, lane = tid & 63;
    const int c = blockIdx.x, h = blockIdx.y, b = blockIdx.z;
    const int p = pq * 16 + (lane & 15);
    const int ng = lane >> 4;
    const size_t rb = (size_t)b * LSEQ;
    const float* xr = xbc + rb * 1152;
    const float* dtr = dtp + rb * 16 + h;
    const float* dAr = dAp + rb * 16 + h;
    const int xhcol = h * 64 + p;
    const int bcol = 1024 + ng * 16;
    const int t_lo = c * QCH, t_hi = t_lo + QCH - 1;

    float hs[16];
#pragma unroll
    for (int j = 0; j < 16; ++j) hs[j] = 0.f;
    float Pp = 1.f;

    float4 BA[4], BB[4];
    float xA, xB, dtA, dtB, dAA, dAB;

    auto LD = [&](int t, float4* Bv, float& xh, float& dtv, float& dAv) {
        const float* r = xr + (size_t)t * 1152;
        xh = r[xhcol];
        Bv[0] = *(const float4*)(r + bcol);
        Bv[1] = *(const float4*)(r + bcol + 4);
        Bv[2] = *(const float4*)(r + bcol + 8);
        Bv[3] = *(const float4*)(r + bcol + 12);
        dtv = dtr[(size_t)t * 16];
        dAv = dAr[(size_t)t * 16];
    };
    auto STEP = [&](const float4* Bv, float xh, float dtv, float dAv) {
        const float dtx = dtv * xh;
        Pp *= dAv;
        const float* Bf = (const float*)Bv;
#pragma unroll
        for (int j = 0; j < 16; ++j)
            hs[j] = fmaf(hs[j], dAv, dtx * Bf[j]);
    };

    LD(t_hi, BA, xA, dtA, dAA);
    for (int s = 0; s < QCH; s += 2) {
        LD(t_hi - s - 1, BB, xB, dtB, dAB);
        STEP(BA, xA, dtA, dAA);
        if (s + 2 < QCH) LD(t_hi - s - 2, BA, xA, dtA, dAA);
        STEP(BB, xB, dtB, dAB);
    }

    float* sp = sbuf + (((size_t)(b * 16 + h) * NCH + c) * 4096) + p * 64 + ng * 16;
    *(float4*)(sp + 0)  = make_float4(hs[0],  hs[1],  hs[2],  hs[3]);
    *(float4*)(sp + 4)  = make_float4(hs[4],  hs[5],  hs[6],  hs[7]);
    *(float4*)(sp + 8)  = make_float4(hs[8],  hs[9],  hs[10], hs[11]);
    *(float4*)(sp + 12) = make_float4(hs[12], hs[13], hs[14], hs[15]);
    if (tid == 0) Pbuf[(b * 16 + h) * NCH + c] = Pp;
}

__global__ __launch_bounds__(256)
void scan_combine(float* __restrict__ sbuf, const float* __restrict__ Pbuf)
{
    const int tid = threadIdx.x;
    const int pq = tid >> 6, lane = tid & 63;
    const int h = blockIdx.y, b = blockIdx.z;
    const int p = pq * 16 + (lane & 15);
    const int ng = lane >> 4;
    const size_t base = (size_t)(b * 16 + h) * NCH;

    float carry[16];
#pragma unroll
    for (int j = 0; j < 16; ++j) carry[j] = 0.f;

    auto sp_at = [&](int c) {
        return sbuf + (base + c) * 4096 + p * 64 + ng * 16;
    };

    float4 L0 = *(const float4*)(sp_at(NCH - 1) + 0);
    float4 L1 = *(const float4*)(sp_at(NCH - 1) + 4);
    float4 L2 = *(const float4*)(sp_at(NCH - 1) + 8);
    float4 L3 = *(const float4*)(sp_at(NCH - 1) + 12);
    float Pn = Pbuf[base + NCH - 1];

    for (int c = NCH - 1; c >= 0; --c) {
        float lv[16] = {L0.x, L0.y, L0.z, L0.w, L1.x, L1.y, L1.z, L1.w,
                        L2.x, L2.y, L2.z, L2.w, L3.x, L3.y, L3.z, L3.w};
        float Pc = Pn;
        if (c > 0) {
            float* spn = sp_at(c - 1);
            L0 = *(const float4*)(spn + 0);
            L1 = *(const float4*)(spn + 4);
            L2 = *(const float4*)(spn + 8);
            L3 = *(const float4*)(spn + 12);
            Pn = Pbuf[base + c - 1];
        }
        float* sp = sp_at(c);
        *(float4*)(sp + 0)  = make_float4(carry[0],  carry[1],  carry[2],  carry[3]);
        *(float4*)(sp + 4)  = make_float4(carry[4],  carry[5],  carry[6],  carry[7]);
        *(float4*)(sp + 8)  = make_float4(carry[8],  carry[9],  carry[10], carry[11]);
        *(float4*)(sp + 12) = make_float4(carry[12], carry[13], carry[14], carry[15]);
#pragma unroll
        for (int j = 0; j < 16; ++j)
            carry[j] = fmaf(carry[j], Pc, lv[j]);
    }
}

// pass 3: seeded rerun; fuses D-residual + z-gate; writes gated bf16
__global__ __launch_bounds__(256)
void scan_final(const float* __restrict__ xbc, const float* __restrict__ dtp,
                const float* __restrict__ dAp, const float* __restrict__ Dvec,
                const float* __restrict__ sbuf, const ushort* __restrict__ zb,
                ushort* __restrict__ gz)
{
    const int tid = threadIdx.x;
    const int pq = tid >> 6, lane = tid & 63;
    const int c = blockIdx.x, h = blockIdx.y, b = blockIdx.z;
    const int p = pq * 16 + (lane & 15);
    const int ng = lane >> 4;
    const float Dh = Dvec[h];
    const size_t rb = (size_t)b * LSEQ;
    const float* xr = xbc + rb * 1152;
    const float* dtr = dtp + rb * 16 + h;
    const float* dAr = dAp + rb * 16 + h;
    const ushort* zrow = zb + rb * NPAD + h * 64 + p;
    ushort* gzrow = gz + rb * 1024 + h * 64 + p;
    const int xhcol = h * 64 + p;
    const int bcol = 1024 + ng * 16;
    const int ccol = 1088 + ng * 16;
    const int t_lo = c * QCH, t_hi = t_lo + QCH - 1;

    const float* sp = sbuf + (((size_t)(b * 16 + h) * NCH + c) * 4096) + p * 64 + ng * 16;
    float4 H0 = *(const float4*)(sp + 0);
    float4 H1 = *(const float4*)(sp + 4);
    float4 H2 = *(const float4*)(sp + 8);
    float4 H3 = *(const float4*)(sp + 12);
    float hs[16] = {H0.x, H0.y, H0.z, H0.w, H1.x, H1.y, H1.z, H1.w,
                    H2.x, H2.y, H2.z, H2.w, H3.x, H3.y, H3.z, H3.w};

    float4 BA[4], BB[4], CA[4], CB[4];
    float xA, xB, dtA, dtB, dAA, dAB;

    auto LD = [&](int t, float4* Bv, float4* Cv, float& xh, float& dtv, float& dAv) {
        const float* r = xr + (size_t)t * 1152;
        xh = r[xhcol];
        Bv[0] = *(const float4*)(r + bcol);
        Bv[1] = *(const float4*)(r + bcol + 4);
        Bv[2] = *(const float4*)(r + bcol + 8);
        Bv[3] = *(const float4*)(r + bcol + 12);
        Cv[0] = *(const float4*)(r + ccol);
        Cv[1] = *(const float4*)(r + ccol + 4);
        Cv[2] = *(const float4*)(r + ccol + 8);
        Cv[3] = *(const float4*)(r + ccol + 12);
        dtv = dtr[(size_t)t * 16];
        dAv = dAr[(size_t)t * 16];
    };
    auto STEP = [&](const float4* Bv, const float4* Cv, float xh, float dtv,
                    float dAv, int t) {
        const float dtx = dtv * xh;
        float acc = 0.f;
        const float* Bf = (const float*)Bv;
        const float* Cf = (const float*)Cv;
#pragma unroll
        for (int j = 0; j < 16; ++j) {
            hs[j] = fmaf(hs[j], dAv, dtx * Bf[j]);
            acc = fmaf(hs[j], Cf[j], acc);
        }
        acc += __shfl_xor(acc, 16);
        acc += __shfl_xor(acc, 32);
        if (ng == 0) {
            float yv = fmaf(Dh, xh, acc);
            float zv = bf2f(zrow[(size_t)t * NPAD]);
            float g = yv * (zv / (1.f + __expf(-zv)));
            gzrow[(size_t)t * 1024] = f2bf(g);
        }
    };

    LD(t_hi, BA, CA, xA, dtA, dAA);
    for (int s = 0; s < QCH; s += 2) {
        LD(t_hi - s - 1, BB, CB, xB, dtB, dAB);
        STEP(BA, CA, xA, dtA, dAA, t_hi - s);
        if (s + 2 < QCH) LD(t_hi - s - 2, BA, CA, xA, dtA, dAA);
        STEP(BB, CB, xB, dtB, dAB, t_hi - s - 1);
    }
}

// ---------------------------------------------------------------------------
// RMS-norm over 1024 of gated values (bf16 in/out)
// ---------------------------------------------------------------------------
__global__ __launch_bounds__(256)
void rms_k(const ushort* __restrict__ gz, const float* __restrict__ rw,
           ushort* __restrict__ out)
{
    const int row = blockIdx.x;
    const int tid = threadIdx.x;
    float g[4];
    float ss = 0.f;
#pragma unroll
    for (int i = 0; i < 4; ++i) {
        int c = i * 256 + tid;
        float gv = bf2f(gz[(size_t)row * 1024 + c]);
        g[i] = gv;
        ss += gv * gv;
    }
#pragma unroll
    for (int off = 32; off > 0; off >>= 1) ss += __shfl_xor(ss, off);
    __shared__ float red[4];
    if ((tid & 63) == 0) red[tid >> 6] = ss;
    __syncthreads();
    ss = red[0] + red[1] + red[2] + red[3];
    const float inv = rsqrtf(ss * (1.f / 1024.f) + 1e-5f);
#pragma unroll
    for (int i = 0; i < 4; ++i) {
        int c = i * 256 + tid;
        out[(size_t)row * 1024 + c] = f2bf(g[i] * inv * rw[c]);
    }
}

// ---------------------------------------------------------------------------
// LayerNorm over 512, fp32 in, bf16 out
// ---------------------------------------------------------------------------
__global__ __launch_bounds__(256)
void layernorm_k(const float* __restrict__ x, const float* __restrict__ gg,
                 const float* __restrict__ bb, ushort* __restrict__ out)
{
    const int row = blockIdx.x;
    const int tid = threadIdx.x;
    float x0 = x[(size_t)row * 512 + tid];
    float x1 = x[(size_t)row * 512 + 256 + tid];
    float s = x0 + x1, ss = x0 * x0 + x1 * x1;
#pragma unroll
    for (int off = 32; off > 0; off >>= 1) {
        s += __shfl_xor(s, off);
        ss += __shfl_xor(ss, off);
    }
    __shared__ float rs[4], rss[4];
    if ((tid & 63) == 0) { rs[tid >> 6] = s; rss[tid >> 6] = ss; }
    __syncthreads();
    s = rs[0] + rs[1] + rs[2] + rs[3];
    ss = rss[0] + rss[1] + rss[2] + rss[3];
    const float mean = s * (1.f / 512.f);
    const float var = ss * (1.f / 512.f) - mean * mean;
    const float inv = rsqrtf(var + 1e-5f);
    out[(size_t)row * 512 + tid]       = f2bf((x0 - mean) * inv * gg[tid] + bb[tid]);
    out[(size_t)row * 512 + 256 + tid] = f2bf((x1 - mean) * inv * gg[256 + tid] + bb[256 + tid]);
}

// ---------------------------------------------------------------------------
extern "C" void kernel_launch(void* const* d_in, const int* in_sizes, int n_in,
                              void* d_out, int out_size, void* d_ws, size_t ws_size,
                              hipStream_t stream)
{
    const float* x         = (const float*)d_in[0];
    const float* in_proj_w = (const float*)d_in[1];   // (2192, 512)
    const float* conv_w    = (const float*)d_in[2];   // (1152, 4)
    const float* conv_b    = (const float*)d_in[3];
    const float* dt_bias   = (const float*)d_in[4];   // (16,)
    const float* A_log     = (const float*)d_in[5];
    const float* Dv        = (const float*)d_in[6];
    const float* rms_w     = (const float*)d_in[7];
    const float* out_proj_w= (const float*)d_in[8];   // (512, 1024)
    const float* ln_g      = (const float*)d_in[9];
    const float* ln_b      = (const float*)d_in[10];
    const float* w1        = (const float*)d_in[11];  // (1024, 1024)
    const float* b1        = (const float*)d_in[12];
    const float* w2        = (const float*)d_in[13];  // (512, 1024)
    const float* b2        = (const float*)d_in[14];
    float* out = (float*)d_out;
    char* base = (char*)d_ws;

    // workspace layout (byte offsets), liveness-safe reuse:
    ushort* g1out = (ushort*)(base);                   // [T,2304] bf16  75.5 MB
    float*  xbcc  = (float*) (base + 75497472);        // [T,1152] f32   75.5 MB
    ushort* gz    = (ushort*)(base + 150994944);       // [T,1024] bf16  33.5 MB
    ushort* xbf   = (ushort*)(base + 150994944);       // [T,512] bf16 (dead before gz written)
    float*  dtb   = (float*) (base + 184549376);       // [T,16]          1 MB
    float*  dab   = (float*) (base + 185597952);       // [T,16]          1 MB
    ushort* wip   = (ushort*)(base + 186646528);       // [2304,512] bf16 2.36 MB
    ushort* w1eb  = (ushort*)(base + 189005824);       // [1024,512] bf16 1 MB
    ushort* wopb  = (ushort*)(base + 190054400);       // [512,1024] bf16 1 MB
    ushort* w2b   = (ushort*)(base + 191102976);       // [512,1024] bf16 1 MB
    float*  Pbuf  = (float*) (base + 192151552);       // [2048]
    // reuse after scan_final:
    ushort* vg  = (ushort*)xbcc;                       // [T,1024] bf16 (xbcc dead)
    float*  y2  = (float*)base;                        // [T,512] f32  (g1out dead)
    ushort* yln = (ushort*)(base + 33554432);          // [T,512] bf16 (in g1out region)
    ushort* h1  = gz;                                  // [T,1024] bf16 (gz dead after rms)
    // chunk states: 4*16*NCH*4096 f32 == out_size exactly; d_out dead until MLP2
    float* sbuf = out;

    // ---- casts (weights + x) ----
    cast_x_k    <<<(TTOK * 512 / 4 + 255) / 256, 256, 0, stream>>>((const float4*)x, (ushort4*)xbf, TTOK * 512 / 4);
    cast_inproj_k<<<(NPAD * 512 / 4 + 255) / 256, 256, 0, stream>>>(in_proj_w, wip);
    w1eff_k     <<<(1024 * 512 / 4 + 255) / 256, 256, 0, stream>>>(w1, w1eb);
    cast_x_k    <<<(512 * 1024 / 4 + 255) / 256, 256, 0, stream>>>((const float4*)out_proj_w, (ushort4*)wopb, 512 * 1024 / 4);
    cast_x_k    <<<(512 * 1024 / 4 + 255) / 256, 256, 0, stream>>>((const float4*)w2, (ushort4*)w2b, 512 * 1024 / 4);

    // ---- in_proj (single padded GEMM: z | xBC | dt_raw) ----
    gemm_mfma<0, ushort><<<dim3(NPAD / 128, TTOK / 128), 256, 0, stream>>>(
        xbf, wip, nullptr, g1out, TTOK, NPAD, 512);

    dt_kernel<<<(TTOK * 16 + 255) / 256, 256, 0, stream>>>(g1out, dt_bias, A_log, dtb, dab, TTOK * 16);
    conv_silu<<<dim3(18, TTOK), 64, 0, stream>>>(g1out, conv_w, conv_b, xbcc);

    // ---- chunked scan ----
    scan_local  <<<dim3(NCH, 16, 4), 256, 0, stream>>>(xbcc, dtb, dab, sbuf, Pbuf);
    scan_combine<<<dim3(1, 16, 4),   256, 0, stream>>>(sbuf, Pbuf);
    scan_final  <<<dim3(NCH, 16, 4), 256, 0, stream>>>(xbcc, dtb, dab, Dv, sbuf, g1out, gz);

    // ---- norm + projections + MLP ----
    rms_k<<<TTOK, 256, 0, stream>>>(gz, rms_w, vg);
    gemm_mfma<0, float><<<dim3(512 / 128, TTOK / 128), 256, 0, stream>>>(
        vg, wopb, nullptr, y2, TTOK, 512, 1024);
    layernorm_k<<<TTOK, 256, 0, stream>>>(y2, ln_g, ln_b, yln);
    gemm_mfma<1, ushort><<<dim3(1024 / 128, TTOK / 128), 256, 0, stream>>>(
        yln, w1eb, b1, h1, TTOK, 1024, 512);
    gemm_mfma<0, float><<<dim3(512 / 128, TTOK / 128), 256, 0, stream>>>(
        h1, w2b, b2, out, TTOK, 512, 1024);
}

// Round 4
// 518.705 us; speedup vs baseline: 6.6958x; 1.6679x over previous
//
#include <hip/hip_runtime.h>
#include <cstddef>
#include <cstdint>
#include <math.h>

// Problem constants
#define LSEQ   4096
#define BATCH  4
#define TTOK   (LSEQ * BATCH)      // 16384 rows
#define QCH    128                 // scan chunk length
#define NCH    (LSEQ / QCH)        // 32 chunks per sequence
#define NPAD   2304                // in_proj N padded to 18*128
// D_MODEL=512, D_INNER=1024, CONV_DIM=1152, NHEADS=16, HEADDIM=64, D_STATE=64
// g1out layout (ld 2304): [0,1024) z | [1024,2176) xBC | [2176,2192) dt_raw | pad
// Scan runs in reversed-time index r = 4095 - l (forward scan in r).

typedef __attribute__((ext_vector_type(8))) short short8;
typedef __attribute__((ext_vector_type(4))) float floatx4;

// ---- bf16 helpers (manual, RNE) ----
__device__ __forceinline__ float bf2f(ushort u) {
    union { unsigned int i; float f; } v; v.i = ((unsigned int)u) << 16; return v.f;
}
__device__ __forceinline__ ushort f2bf(float f) {
    union { float f; unsigned int i; } v; v.f = f;
    unsigned int r = v.i + 0x7fffu + ((v.i >> 16) & 1u);
    return (ushort)(r >> 16);
}

__device__ __forceinline__ void storev(float* p, float v)  { *p = v; }
__device__ __forceinline__ void storev(ushort* p, float v) { *p = f2bf(v); }

// async 16B global -> LDS (wave-uniform LDS base + lane*16)
__device__ __forceinline__ void gload_lds16(const ushort* g, short* l) {
    __builtin_amdgcn_global_load_lds(
        (const __attribute__((address_space(1))) void*)g,
        (__attribute__((address_space(3))) void*)l, 16, 0, 0);
}

// ---------------------------------------------------------------------------
// bf16 MFMA GEMM: C[M,N] = act(A[M,K] @ W[N,K]^T + bias)  (unchanged, works)
// ---------------------------------------------------------------------------
template<int ACT, typename OutT>   // ACT: 0 none, 1 silu
__global__ __launch_bounds__(256)
void gemm_mfma(const ushort* __restrict__ A, const ushort* __restrict__ W,
               const float* __restrict__ bias, OutT* __restrict__ C,
               int M, int N, int K)
{
    __shared__ __align__(16) short As[128 * 32];
    __shared__ __align__(16) short Ws[128 * 32];
    const int tid = threadIdx.x;
    const int w = tid >> 6, l = tid & 63;
    const int m0 = blockIdx.y * 128, n0 = blockIdx.x * 128;

    const ushort* ga[2]; const ushort* gw[2];
    short* la[2]; short* lw[2];
#pragma unroll
    for (int k = 0; k < 2; ++k) {
        int row = (k * 256 + tid) >> 2;
        int c = tid & 3;
        int q = c ^ (row & 3);
        ga[k] = A + (size_t)(m0 + row) * K + q * 8;
        gw[k] = W + (size_t)(n0 + row) * K + q * 8;
        la[k] = As + (k * 64 + w * 16) * 32;
        lw[k] = Ws + (k * 64 + w * 16) * 32;
    }

    const int lm = l & 15, quad = l >> 4;
    const int wm = w & 1, wn = w >> 1;
    int aoff[4], boff[4];
#pragma unroll
    for (int i = 0; i < 4; ++i) {
        int ra = wm * 64 + i * 16 + lm;
        aoff[i] = ra * 32 + ((quad ^ (ra & 3)) * 8);
        int rb = wn * 64 + i * 16 + lm;
        boff[i] = rb * 32 + ((quad ^ (rb & 3)) * 8);
    }

    floatx4 acc[4][4];
#pragma unroll
    for (int i = 0; i < 4; ++i)
#pragma unroll
        for (int j = 0; j < 4; ++j) acc[i][j] = (floatx4){0.f, 0.f, 0.f, 0.f};

    for (int k0 = 0; k0 < K; k0 += 32) {
#pragma unroll
        for (int k = 0; k < 2; ++k) {
            gload_lds16(ga[k] + k0, la[k]);
            gload_lds16(gw[k] + k0, lw[k]);
        }
        __syncthreads();
        short8 af[4], bfr[4];
#pragma unroll
        for (int i = 0; i < 4; ++i) af[i]  = *(const short8*)(As + aoff[i]);
#pragma unroll
        for (int j = 0; j < 4; ++j) bfr[j] = *(const short8*)(Ws + boff[j]);
#pragma unroll
        for (int i = 0; i < 4; ++i)
#pragma unroll
            for (int j = 0; j < 4; ++j)
                acc[i][j] = __builtin_amdgcn_mfma_f32_16x16x32_bf16(
                    af[i], bfr[j], acc[i][j], 0, 0, 0);
        __syncthreads();
    }

#pragma unroll
    for (int i = 0; i < 4; ++i) {
        const int rbase = m0 + wm * 64 + i * 16 + quad * 4;
#pragma unroll
        for (int r = 0; r < 4; ++r) {
#pragma unroll
            for (int j = 0; j < 4; ++j) {
                const int col = n0 + wn * 64 + j * 16 + lm;
                float v = acc[i][j][r];
                if (bias) v += bias[col];
                if (ACT == 1) v = v / (1.f + __expf(-v));
                storev(&C[(size_t)(rbase + r) * N + col], v);
            }
        }
    }
}

// ---------------------------------------------------------------------------
// casts
// ---------------------------------------------------------------------------
__global__ __launch_bounds__(256)
void cast_x_k(const float4* __restrict__ in, ushort4* __restrict__ out, int n4)
{
    int i = blockIdx.x * 256 + threadIdx.x;
    if (i >= n4) return;
    float4 v = in[i];
    ushort4 o;
    o.x = f2bf(v.x); o.y = f2bf(v.y); o.z = f2bf(v.z); o.w = f2bf(v.w);
    out[i] = o;
}

__global__ __launch_bounds__(256)
void cast_inproj_k(const float* __restrict__ w, ushort* __restrict__ o)
{
    int i = blockIdx.x * 256 + threadIdx.x;
    int i4 = i * 4;
    if (i4 >= NPAD * 512) return;
    int row = i4 >> 9;
    ushort4 v;
    if (row < 2192) {
        const float4 s = *(const float4*)(w + (size_t)i4);
        v.x = f2bf(s.x); v.y = f2bf(s.y); v.z = f2bf(s.z); v.w = f2bf(s.w);
    } else {
        v.x = v.y = v.z = v.w = 0;
    }
    *(ushort4*)(o + i4) = v;
}

// w1eff[j,d] = bf16(w1[j,d] + w1[j,512+d])
__global__ __launch_bounds__(256)
void w1eff_k(const float* __restrict__ w1, ushort* __restrict__ we)
{
    int i = blockIdx.x * 256 + threadIdx.x;
    int i4 = i * 4;
    if (i4 >= 1024 * 512) return;
    int j = i4 >> 9, d = i4 & 511;
    float4 a = *(const float4*)(w1 + (size_t)j * 1024 + d);
    float4 b = *(const float4*)(w1 + (size_t)j * 1024 + 512 + d);
    ushort4 v;
    v.x = f2bf(a.x + b.x); v.y = f2bf(a.y + b.y);
    v.z = f2bf(a.z + b.z); v.w = f2bf(a.w + b.w);
    *(ushort4*)(we + i4) = v;
}

// ---------------------------------------------------------------------------
// dt = softplus(raw + dt_bias); also log(dA) = dt*(-exp(A_log)).
// Output indexed [b][h][r] with r = reversed-time (scan-forward) index.
// ---------------------------------------------------------------------------
__global__ __launch_bounds__(256)
void dt_kernel(const ushort* __restrict__ raw, const float* __restrict__ dt_bias,
               const float* __restrict__ A_log, float* __restrict__ dtr,
               float* __restrict__ ldar, int n)
{
    int i = blockIdx.x * 256 + threadIdx.x;
    if (i >= n) return;
    int hh = i & 15;
    int row = i >> 4;
    float v = bf2f(raw[(size_t)row * NPAD + 2176 + hh]) + dt_bias[hh];
    float s = (v > 20.f) ? v : log1pf(expf(v));
    float Ah = -expf(A_log[hh]);
    int b = row >> 12;
    int r = 4095 - (row & 4095);
    size_t idx = ((size_t)(b * 16 + hh)) * LSEQ + r;
    dtr[idx] = s;
    ldar[idx] = s * Ah;
}

// ---------------------------------------------------------------------------
// seg = inclusive cumsum of log(dA) within each chunk (in r-order);
// alpha(tau) = exp(seg_last - seg_tau) * dt_tau ;  P = exp(seg_last)
// ---------------------------------------------------------------------------
__global__ __launch_bounds__(128)
void seg_scan(const float* __restrict__ ldar, const float* __restrict__ dtr,
              float* __restrict__ segb, float* __restrict__ alphab,
              float* __restrict__ Pb)
{
    __shared__ float s[128];
    const int tid = threadIdx.x;
    const int c = blockIdx.x, h = blockIdx.y, b = blockIdx.z;
    const int bh = b * 16 + h;
    const size_t idx = (size_t)bh * LSEQ + c * QCH + tid;
    s[tid] = ldar[idx];
    __syncthreads();
#pragma unroll
    for (int off = 1; off < 128; off <<= 1) {
        float t = (tid >= off) ? s[tid - off] : 0.f;
        __syncthreads();
        s[tid] += t;
        __syncthreads();
    }
    float seg = s[tid];
    float last = s[127];
    segb[idx] = seg;
    alphab[idx] = __expf(last - seg) * dtr[idx];
    if (tid == 127) Pb[bh * NCH + c] = __expf(last);
}

// ---------------------------------------------------------------------------
// Anti-causal depthwise conv + silu; bf16 out split into xh [T,1024] and
// bc [T,128] (B|C).
// ---------------------------------------------------------------------------
__global__ __launch_bounds__(64)
void conv_silu(const ushort* __restrict__ raw, const float* __restrict__ cw,
               const float* __restrict__ cb, ushort* __restrict__ xh,
               ushort* __restrict__ bc)
{
    const int c = blockIdx.x * 64 + threadIdx.x;   // 0..1151
    const int row = blockIdx.y;                    // b*LSEQ + l
    const int l = row & (LSEQ - 1);
    float acc = cb[c];
#pragma unroll
    for (int k = 0; k < 4; ++k) {
        int ll = l + 3 - k;
        if (ll < LSEQ)
            acc = fmaf(cw[c * 4 + k], bf2f(raw[(size_t)(row + 3 - k) * NPAD + 1024 + c]), acc);
    }
    acc = acc / (1.f + __expf(-acc));
    ushort o = f2bf(acc);
    if (c < 1024) xh[(size_t)row * 1024 + c] = o;
    else          bc[(size_t)row * 128 + (c - 1024)] = o;
}

// ---------------------------------------------------------------------------
// SSD pass A: per tile (c,h,b), chunk end-state
//   L[p,n] = sum_tau XT[p,tau] * (alpha(tau)*B[tau,n])
// 256 thr = 4 waves; wave w -> p rows [w*16,+16). Output sbuf[tile][p*64+n].
// ---------------------------------------------------------------------------
__global__ __launch_bounds__(256)
void ssd_states(const ushort* __restrict__ xh, const ushort* __restrict__ bc,
                const float* __restrict__ alphab, float* __restrict__ sbuf)
{
    __shared__ __align__(16) ushort XT[64 * 136];
    __shared__ __align__(16) ushort BpT[64 * 136];
    const int tid = threadIdx.x;
    const int w = tid >> 6, lane = tid & 63;
    const int lm = lane & 15, quad = lane >> 4;
    const int c = blockIdx.x, h = blockIdx.y, b = blockIdx.z;
    const int bh = b * 16 + h;
    const size_t abase = (size_t)bh * LSEQ + c * QCH;

    // stage X transposed [p][tau] and B' transposed [n][tau]
#pragma unroll
    for (int it = 0; it < 8; ++it) {
        int idx = it * 256 + tid;
        int tau = idx >> 4, e4 = (idx & 15) * 4;
        size_t grow = (size_t)b * LSEQ + (LSEQ - 1 - (c * QCH + tau));
        ushort4 xv = *(const ushort4*)(xh + grow * 1024 + h * 64 + e4);
        XT[(e4 + 0) * 136 + tau] = xv.x;
        XT[(e4 + 1) * 136 + tau] = xv.y;
        XT[(e4 + 2) * 136 + tau] = xv.z;
        XT[(e4 + 3) * 136 + tau] = xv.w;
        float al = alphab[abase + tau];
        ushort4 bv = *(const ushort4*)(bc + grow * 128 + e4);
        BpT[(e4 + 0) * 136 + tau] = f2bf(bf2f(bv.x) * al);
        BpT[(e4 + 1) * 136 + tau] = f2bf(bf2f(bv.y) * al);
        BpT[(e4 + 2) * 136 + tau] = f2bf(bf2f(bv.z) * al);
        BpT[(e4 + 3) * 136 + tau] = f2bf(bf2f(bv.w) * al);
    }
    __syncthreads();

    floatx4 L[4];
#pragma unroll
    for (int j = 0; j < 4; ++j) L[j] = (floatx4){0.f, 0.f, 0.f, 0.f};
#pragma unroll
    for (int kc = 0; kc < 4; ++kc) {
        short8 a = *(const short8*)(XT + (w * 16 + lm) * 136 + kc * 32 + quad * 8);
#pragma unroll
        for (int jn = 0; jn < 4; ++jn) {
            short8 bf = *(const short8*)(BpT + (jn * 16 + lm) * 136 + kc * 32 + quad * 8);
            L[jn] = __builtin_amdgcn_mfma_f32_16x16x32_bf16(a, bf, L[jn], 0, 0, 0);
        }
    }
    float* Sp = sbuf + ((size_t)bh * NCH + c) * 4096;
#pragma unroll
    for (int jn = 0; jn < 4; ++jn)
#pragma unroll
        for (int r = 0; r < 4; ++r) {
            int p = w * 16 + quad * 4 + r;
            Sp[p * 64 + jn * 16 + lm] = L[jn][r];
        }
}

// ---------------------------------------------------------------------------
// Combine: sequential over chunks in scan (r) order.
//   h_start(c) = carry (stored back); carry = P_c*carry + L_c
// ---------------------------------------------------------------------------
__global__ __launch_bounds__(256)
void scan_combine(float* __restrict__ sbuf, const float* __restrict__ Pb)
{
    const int tid = threadIdx.x;
    const int h = blockIdx.y, b = blockIdx.z;
    const int bh = b * 16 + h;
    const int off = tid * 16;
    float carry[16];
#pragma unroll
    for (int j = 0; j < 16; ++j) carry[j] = 0.f;
    for (int c = 0; c < NCH; ++c) {
        float* sp = sbuf + ((size_t)bh * NCH + c) * 4096 + off;
        float P = Pb[bh * NCH + c];
        float4 l0 = *(const float4*)(sp + 0);
        float4 l1 = *(const float4*)(sp + 4);
        float4 l2 = *(const float4*)(sp + 8);
        float4 l3 = *(const float4*)(sp + 12);
        *(float4*)(sp + 0)  = make_float4(carry[0],  carry[1],  carry[2],  carry[3]);
        *(float4*)(sp + 4)  = make_float4(carry[4],  carry[5],  carry[6],  carry[7]);
        *(float4*)(sp + 8)  = make_float4(carry[8],  carry[9],  carry[10], carry[11]);
        *(float4*)(sp + 12) = make_float4(carry[12], carry[13], carry[14], carry[15]);
        float lv[16] = {l0.x, l0.y, l0.z, l0.w, l1.x, l1.y, l1.z, l1.w,
                        l2.x, l2.y, l2.z, l2.w, l3.x, l3.y, l3.z, l3.w};
#pragma unroll
        for (int j = 0; j < 16; ++j) carry[j] = fmaf(carry[j], P, lv[j]);
    }
}

// ---------------------------------------------------------------------------
// SSD pass C: per tile, Y = [M o (C B^T)] X + diag(exp(seg)) C h_start^T,
// D folded into mask diagonal, z-gate fused, writes gated bf16.
// ---------------------------------------------------------------------------
__global__ __launch_bounds__(256)
void ssd_y(const ushort* __restrict__ xh, const ushort* __restrict__ bc,
           const float* __restrict__ segb, const float* __restrict__ dtb_,
           const float* __restrict__ Dvec, const float* __restrict__ sbuf,
           const ushort* __restrict__ zb, ushort* __restrict__ gz)
{
    __shared__ __align__(16) char smem[72192];
    ushort* Ct  = (ushort*)smem;            // [128][72]
    ushort* XT  = (ushort*)(smem + 18432);  // [64][136]
    ushort* Bt  = (ushort*)(smem + 35840);  // [128][72]  (dead after GEMM1)
    ushort* Wl  = (ushort*)(smem + 35840);  // [128][136] (overlaps Bt)
    float* segl = (float*)(smem + 70656);   // [128]
    float* dtl  = (float*)(smem + 71168);   // [128]

    const int tid = threadIdx.x;
    const int w = tid >> 6, lane = tid & 63;
    const int lm = lane & 15, quad = lane >> 4;
    const int c = blockIdx.x, h = blockIdx.y, b = blockIdx.z;
    const int bh = b * 16 + h;
    const size_t abase = (size_t)bh * LSEQ + c * QCH;

    if (tid < 128) {
        segl[tid] = segb[abase + tid];
        dtl[tid]  = dtb_[abase + tid];
    }
    // stage B,C natural [tau][n] and X transposed [p][tau]
#pragma unroll
    for (int it = 0; it < 8; ++it) {
        int idx = it * 256 + tid;
        int tau = idx >> 4, e4 = (idx & 15) * 4;
        size_t grow = (size_t)b * LSEQ + (LSEQ - 1 - (c * QCH + tau));
        ushort4 bv = *(const ushort4*)(bc + grow * 128 + e4);
        ushort4 cv = *(const ushort4*)(bc + grow * 128 + 64 + e4);
        *(ushort4*)(Bt + tau * 72 + e4) = bv;
        *(ushort4*)(Ct + tau * 72 + e4) = cv;
        ushort4 xv = *(const ushort4*)(xh + grow * 1024 + h * 64 + e4);
        XT[(e4 + 0) * 136 + tau] = xv.x;
        XT[(e4 + 1) * 136 + tau] = xv.y;
        XT[(e4 + 2) * 136 + tau] = xv.z;
        XT[(e4 + 3) * 136 + tau] = xv.w;
    }
    __syncthreads();

    // GEMM1: G = C . B^T ; wave w owns rows [w*32,+32)
    floatx4 G[2][8];
#pragma unroll
    for (int i = 0; i < 2; ++i)
#pragma unroll
        for (int j = 0; j < 8; ++j) G[i][j] = (floatx4){0.f, 0.f, 0.f, 0.f};
#pragma unroll
    for (int kc = 0; kc < 2; ++kc) {
        short8 a[2];
#pragma unroll
        for (int i = 0; i < 2; ++i)
            a[i] = *(const short8*)(Ct + (w * 32 + i * 16 + lm) * 72 + kc * 32 + quad * 8);
#pragma unroll
        for (int jn = 0; jn < 8; ++jn) {
            short8 bf = *(const short8*)(Bt + (jn * 16 + lm) * 72 + kc * 32 + quad * 8);
#pragma unroll
            for (int i = 0; i < 2; ++i)
                G[i][jn] = __builtin_amdgcn_mfma_f32_16x16x32_bf16(a[i], bf, G[i][jn], 0, 0, 0);
        }
    }
    __syncthreads();   // everyone done reading Bt before Wl overwrites it

    const float Dh = Dvec[h];
    // mask + exp + dt + D-diagonal, write W rows (bf16) to LDS
#pragma unroll
    for (int i = 0; i < 2; ++i) {
        const int taub = w * 32 + i * 16;
#pragma unroll
        for (int jn = 0; jn < 8; ++jn) {
            const int sigma = jn * 16 + lm;
            const float dts = dtl[sigma];
            const float segs = segl[sigma];
#pragma unroll
            for (int r = 0; r < 4; ++r) {
                const int tau = taub + quad * 4 + r;
                float g = G[i][jn][r];
                float wv;
                if (sigma < tau)       wv = dts * g * __expf(segl[tau] - segs);
                else if (sigma == tau) wv = dts * g + Dh;
                else                   wv = 0.f;
                Wl[tau * 136 + sigma] = f2bf(wv);
            }
        }
    }
    // no barrier needed: each wave reads back only its own W rows

    // GEMM2: Y = W.X + (exp(seg) C).H^T
    floatx4 Y[2][4];
#pragma unroll
    for (int i = 0; i < 2; ++i)
#pragma unroll
        for (int j = 0; j < 4; ++j) Y[i][j] = (floatx4){0.f, 0.f, 0.f, 0.f};
#pragma unroll
    for (int kc = 0; kc < 4; ++kc) {
        short8 a[2];
#pragma unroll
        for (int i = 0; i < 2; ++i)
            a[i] = *(const short8*)(Wl + (w * 32 + i * 16 + lm) * 136 + kc * 32 + quad * 8);
#pragma unroll
        for (int jn = 0; jn < 4; ++jn) {
            short8 bf = *(const short8*)(XT + (jn * 16 + lm) * 136 + kc * 32 + quad * 8);
#pragma unroll
            for (int i = 0; i < 2; ++i)
                Y[i][jn] = __builtin_amdgcn_mfma_f32_16x16x32_bf16(a[i], bf, Y[i][jn], 0, 0, 0);
        }
    }
    const float* Hp = sbuf + ((size_t)bh * NCH + c) * 4096;
#pragma unroll
    for (int kc = 0; kc < 2; ++kc) {
        short8 a[2];
#pragma unroll
        for (int i = 0; i < 2; ++i) {
            const int row = w * 32 + i * 16 + lm;
            const float es = __expf(segl[row]);
            short8 craw = *(const short8*)(Ct + row * 72 + kc * 32 + quad * 8);
#pragma unroll
            for (int e = 0; e < 8; ++e)
                a[i][e] = (short)f2bf(bf2f((ushort)craw[e]) * es);
        }
#pragma unroll
        for (int jn = 0; jn < 4; ++jn) {
            const float* hp = Hp + (jn * 16 + lm) * 64 + kc * 32 + quad * 8;
            float4 h0 = *(const float4*)(hp);
            float4 h1 = *(const float4*)(hp + 4);
            short8 bf;
            bf[0] = (short)f2bf(h0.x); bf[1] = (short)f2bf(h0.y);
            bf[2] = (short)f2bf(h0.z); bf[3] = (short)f2bf(h0.w);
            bf[4] = (short)f2bf(h1.x); bf[5] = (short)f2bf(h1.y);
            bf[6] = (short)f2bf(h1.z); bf[7] = (short)f2bf(h1.w);
#pragma unroll
            for (int i = 0; i < 2; ++i)
                Y[i][jn] = __builtin_amdgcn_mfma_f32_16x16x32_bf16(a[i], bf, Y[i][jn], 0, 0, 0);
        }
    }

    // epilogue: z-gate, store gated bf16
#pragma unroll
    for (int i = 0; i < 2; ++i) {
#pragma unroll
        for (int r = 0; r < 4; ++r) {
            const int tau = w * 32 + i * 16 + quad * 4 + r;
            const size_t grow = (size_t)b * LSEQ + (LSEQ - 1 - (c * QCH + tau));
#pragma unroll
            for (int jn = 0; jn < 4; ++jn) {
                const int col = h * 64 + jn * 16 + lm;
                float yv = Y[i][jn][r];
                float zv = bf2f(zb[grow * NPAD + col]);
                float gv = yv * (zv / (1.f + __expf(-zv)));
                gz[grow * 1024 + col] = f2bf(gv);
            }
        }
    }
}

// ---------------------------------------------------------------------------
// RMS-norm over 1024 of gated values (bf16 in/out)
// ---------------------------------------------------------------------------
__global__ __launch_bounds__(256)
void rms_k(const ushort* __restrict__ gz, const float* __restrict__ rw,
           ushort* __restrict__ out)
{
    const int row = blockIdx.x;
    const int tid = threadIdx.x;
    float g[4];
    float ss = 0.f;
#pragma unroll
    for (int i = 0; i < 4; ++i) {
        int c = i * 256 + tid;
        float gv = bf2f(gz[(size_t)row * 1024 + c]);
        g[i] = gv;
        ss += gv * gv;
    }
#pragma unroll
    for (int off = 32; off > 0; off >>= 1) ss += __shfl_xor(ss, off);
    __shared__ float red[4];
    if ((tid & 63) == 0) red[tid >> 6] = ss;
    __syncthreads();
    ss = red[0] + red[1] + red[2] + red[3];
    const float inv = rsqrtf(ss * (1.f / 1024.f) + 1e-5f);
#pragma unroll
    for (int i = 0; i < 4; ++i) {
        int c = i * 256 + tid;
        out[(size_t)row * 1024 + c] = f2bf(g[i] * inv * rw[c]);
    }
}

// ---------------------------------------------------------------------------
// LayerNorm over 512, fp32 in, bf16 out
// ---------------------------------------------------------------------------
__global__ __launch_bounds__(256)
void layernorm_k(const float* __restrict__ x, const float* __restrict__ gg,
                 const float* __restrict__ bb, ushort* __restrict__ out)
{
    const int row = blockIdx.x;
    const int tid = threadIdx.x;
    float x0 = x[(size_t)row * 512 + tid];
    float x1 = x[(size_t)row * 512 + 256 + tid];
    float s = x0 + x1, ss = x0 * x0 + x1 * x1;
#pragma unroll
    for (int off = 32; off > 0; off >>= 1) {
        s += __shfl_xor(s, off);
        ss += __shfl_xor(ss, off);
    }
    __shared__ float rs[4], rss[4];
    if ((tid & 63) == 0) { rs[tid >> 6] = s; rss[tid >> 6] = ss; }
    __syncthreads();
    s = rs[0] + rs[1] + rs[2] + rs[3];
    ss = rss[0] + rss[1] + rss[2] + rss[3];
    const float mean = s * (1.f / 512.f);
    const float var = ss * (1.f / 512.f) - mean * mean;
    const float inv = rsqrtf(var + 1e-5f);
    out[(size_t)row * 512 + tid]       = f2bf((x0 - mean) * inv * gg[tid] + bb[tid]);
    out[(size_t)row * 512 + 256 + tid] = f2bf((x1 - mean) * inv * gg[256 + tid] + bb[256 + tid]);
}

// ---------------------------------------------------------------------------
extern "C" void kernel_launch(void* const* d_in, const int* in_sizes, int n_in,
                              void* d_out, int out_size, void* d_ws, size_t ws_size,
                              hipStream_t stream)
{
    const float* x         = (const float*)d_in[0];
    const float* in_proj_w = (const float*)d_in[1];   // (2192, 512)
    const float* conv_w    = (const float*)d_in[2];   // (1152, 4)
    const float* conv_b    = (const float*)d_in[3];
    const float* dt_bias   = (const float*)d_in[4];   // (16,)
    const float* A_log     = (const float*)d_in[5];
    const float* Dv        = (const float*)d_in[6];
    const float* rms_w     = (const float*)d_in[7];
    const float* out_proj_w= (const float*)d_in[8];   // (512, 1024)
    const float* ln_g      = (const float*)d_in[9];
    const float* ln_b      = (const float*)d_in[10];
    const float* w1        = (const float*)d_in[11];  // (1024, 1024)
    const float* b1        = (const float*)d_in[12];
    const float* w2        = (const float*)d_in[13];  // (512, 1024)
    const float* b2        = (const float*)d_in[14];
    float* out = (float*)d_out;
    char* base = (char*)d_ws;

    // workspace layout (byte offsets), liveness-safe reuse:
    ushort* g1out = (ushort*)(base);                   // [T,2304] bf16   75.5 MB
    ushort* xh_b  = (ushort*)(base + 75497472);        // [T,1024] bf16   33.5 MB
    ushort* bc_b  = (ushort*)(base + 109051904);       // [T,128]  bf16    4.2 MB
    ushort* gz    = (ushort*)(base + 113246208);       // [T,1024] bf16   33.5 MB
    ushort* xbf   = (ushort*)(base + 113246208);       // [T,512] bf16 (dead before gz)
    float*  dtr   = (float*) (base + 146800640);       // [64][4096]       1 MB
    float*  ldar  = (float*) (base + 147849216);       // [64][4096]       1 MB
    float*  segb  = (float*) (base + 148897792);       // [64][4096]       1 MB
    float*  alphab= (float*) (base + 149946368);       // [64][4096]       1 MB
    ushort* wip   = (ushort*)(base + 150994944);       // [2304,512] bf16
    ushort* w1eb  = (ushort*)(base + 153354240);       // [1024,512] bf16
    ushort* wopb  = (ushort*)(base + 154402816);       // [512,1024] bf16
    ushort* w2b   = (ushort*)(base + 155451392);       // [512,1024] bf16
    float*  Pbuf  = (float*) (base + 156499968);       // [64*32]
    // post-scan reuse:
    ushort* vg  = xh_b;                                // [T,1024] bf16 (xh dead)
    float*  y2  = (float*)base;                        // [T,512] f32 (g1out dead)
    ushort* yln = (ushort*)(base + 33554432);          // [T,512] bf16
    ushort* h1  = gz;                                  // [T,1024] bf16 (gz dead)
    // chunk states: 64 tiles/seq-head x 4096 f32 == out_size; d_out dead until MLP2
    float* sbuf = out;

    // ---- casts ----
    cast_x_k    <<<(TTOK * 512 / 4 + 255) / 256, 256, 0, stream>>>((const float4*)x, (ushort4*)xbf, TTOK * 512 / 4);
    cast_inproj_k<<<(NPAD * 512 / 4 + 255) / 256, 256, 0, stream>>>(in_proj_w, wip);
    w1eff_k     <<<(1024 * 512 / 4 + 255) / 256, 256, 0, stream>>>(w1, w1eb);
    cast_x_k    <<<(512 * 1024 / 4 + 255) / 256, 256, 0, stream>>>((const float4*)out_proj_w, (ushort4*)wopb, 512 * 1024 / 4);
    cast_x_k    <<<(512 * 1024 / 4 + 255) / 256, 256, 0, stream>>>((const float4*)w2, (ushort4*)w2b, 512 * 1024 / 4);

    // ---- in_proj ----
    gemm_mfma<0, ushort><<<dim3(NPAD / 128, TTOK / 128), 256, 0, stream>>>(
        xbf, wip, nullptr, g1out, TTOK, NPAD, 512);

    dt_kernel<<<(TTOK * 16 + 255) / 256, 256, 0, stream>>>(g1out, dt_bias, A_log, dtr, ldar, TTOK * 16);
    seg_scan<<<dim3(NCH, 16, 4), 128, 0, stream>>>(ldar, dtr, segb, alphab, Pbuf);
    conv_silu<<<dim3(18, TTOK), 64, 0, stream>>>(g1out, conv_w, conv_b, xh_b, bc_b);

    // ---- SSD chunked scan ----
    ssd_states  <<<dim3(NCH, 16, 4), 256, 0, stream>>>(xh_b, bc_b, alphab, sbuf);
    scan_combine<<<dim3(1, 16, 4),   256, 0, stream>>>(sbuf, Pbuf);
    ssd_y       <<<dim3(NCH, 16, 4), 256, 0, stream>>>(xh_b, bc_b, segb, dtr, Dv, sbuf, g1out, gz);

    // ---- norm + projections + MLP ----
    rms_k<<<TTOK, 256, 0, stream>>>(gz, rms_w, vg);
    gemm_mfma<0, float><<<dim3(512 / 128, TTOK / 128), 256, 0, stream>>>(
        vg, wopb, nullptr, y2, TTOK, 512, 1024);
    layernorm_k<<<TTOK, 256, 0, stream>>>(y2, ln_g, ln_b, yln);
    gemm_mfma<1, ushort><<<dim3(1024 / 128, TTOK / 128), 256, 0, stream>>>(
        yln, w1eb, b1, h1, TTOK, 1024, 512);
    gemm_mfma<0, float><<<dim3(512 / 128, TTOK / 128), 256, 0, stream>>>(
        h1, w2b, b2, out, TTOK, 512, 1024);
}

// Round 5
// 513.062 us; speedup vs baseline: 6.7695x; 1.0110x over previous
//
#include <hip/hip_runtime.h>
#include <cstddef>
#include <cstdint>
#include <math.h>

// Problem constants
#define LSEQ   4096
#define BATCH  4
#define TTOK   (LSEQ * BATCH)      // 16384 rows
#define QCH    128                 // scan chunk length
#define NCH    (LSEQ / QCH)        // 32 chunks per sequence
#define NPAD   2304                // in_proj N padded to 18*128
// D_MODEL=512, D_INNER=1024, CONV_DIM=1152, NHEADS=16, HEADDIM=64, D_STATE=64
// g1out layout (ld 2304): [0,1024) z | [1024,2176) xBC | [2176,2192) dt_raw | pad
// Scan runs in reversed-time index r = 4095 - l (forward scan in r).

typedef __attribute__((ext_vector_type(8))) short short8;
typedef __attribute__((ext_vector_type(8))) unsigned short ushortx8;
typedef __attribute__((ext_vector_type(4))) float floatx4;

// ---- bf16 helpers (manual, RNE) ----
__device__ __forceinline__ float bf2f(ushort u) {
    union { unsigned int i; float f; } v; v.i = ((unsigned int)u) << 16; return v.f;
}
__device__ __forceinline__ ushort f2bf(float f) {
    union { float f; unsigned int i; } v; v.f = f;
    unsigned int r = v.i + 0x7fffu + ((v.i >> 16) & 1u);
    return (ushort)(r >> 16);
}

__device__ __forceinline__ void storev(float* p, float v)  { *p = v; }
__device__ __forceinline__ void storev(ushort* p, float v) { *p = f2bf(v); }

// async 16B global -> LDS (wave-uniform LDS base + lane*16)
__device__ __forceinline__ void gload_lds16(const ushort* g, short* l) {
    __builtin_amdgcn_global_load_lds(
        (const __attribute__((address_space(1))) void*)g,
        (__attribute__((address_space(3))) void*)l, 16, 0, 0);
}

// ---------------------------------------------------------------------------
// bf16 MFMA GEMM: C[M,N] = act(A[M,K] @ W[N,K]^T + bias)
// ---------------------------------------------------------------------------
template<int ACT, typename OutT>   // ACT: 0 none, 1 silu
__global__ __launch_bounds__(256)
void gemm_mfma(const ushort* __restrict__ A, const ushort* __restrict__ W,
               const float* __restrict__ bias, OutT* __restrict__ C,
               int M, int N, int K)
{
    __shared__ __align__(16) short As[128 * 32];
    __shared__ __align__(16) short Ws[128 * 32];
    const int tid = threadIdx.x;
    const int w = tid >> 6, l = tid & 63;
    const int m0 = blockIdx.y * 128, n0 = blockIdx.x * 128;

    const ushort* ga[2]; const ushort* gw[2];
    short* la[2]; short* lw[2];
#pragma unroll
    for (int k = 0; k < 2; ++k) {
        int row = (k * 256 + tid) >> 2;
        int c = tid & 3;
        int q = c ^ (row & 3);
        ga[k] = A + (size_t)(m0 + row) * K + q * 8;
        gw[k] = W + (size_t)(n0 + row) * K + q * 8;
        la[k] = As + (k * 64 + w * 16) * 32;
        lw[k] = Ws + (k * 64 + w * 16) * 32;
    }

    const int lm = l & 15, quad = l >> 4;
    const int wm = w & 1, wn = w >> 1;
    int aoff[4], boff[4];
#pragma unroll
    for (int i = 0; i < 4; ++i) {
        int ra = wm * 64 + i * 16 + lm;
        aoff[i] = ra * 32 + ((quad ^ (ra & 3)) * 8);
        int rb = wn * 64 + i * 16 + lm;
        boff[i] = rb * 32 + ((quad ^ (rb & 3)) * 8);
    }

    floatx4 acc[4][4];
#pragma unroll
    for (int i = 0; i < 4; ++i)
#pragma unroll
        for (int j = 0; j < 4; ++j) acc[i][j] = (floatx4){0.f, 0.f, 0.f, 0.f};

    for (int k0 = 0; k0 < K; k0 += 32) {
#pragma unroll
        for (int k = 0; k < 2; ++k) {
            gload_lds16(ga[k] + k0, la[k]);
            gload_lds16(gw[k] + k0, lw[k]);
        }
        __syncthreads();
        short8 af[4], bfr[4];
#pragma unroll
        for (int i = 0; i < 4; ++i) af[i]  = *(const short8*)(As + aoff[i]);
#pragma unroll
        for (int j = 0; j < 4; ++j) bfr[j] = *(const short8*)(Ws + boff[j]);
#pragma unroll
        for (int i = 0; i < 4; ++i)
#pragma unroll
            for (int j = 0; j < 4; ++j)
                acc[i][j] = __builtin_amdgcn_mfma_f32_16x16x32_bf16(
                    af[i], bfr[j], acc[i][j], 0, 0, 0);
        __syncthreads();
    }

#pragma unroll
    for (int i = 0; i < 4; ++i) {
        const int rbase = m0 + wm * 64 + i * 16 + quad * 4;
#pragma unroll
        for (int r = 0; r < 4; ++r) {
#pragma unroll
            for (int j = 0; j < 4; ++j) {
                const int col = n0 + wn * 64 + j * 16 + lm;
                float v = acc[i][j][r];
                if (bias) v += bias[col];
                if (ACT == 1) v = v / (1.f + __expf(-v));
                storev(&C[(size_t)(rbase + r) * N + col], v);
            }
        }
    }
}

// ---------------------------------------------------------------------------
// casts
// ---------------------------------------------------------------------------
__global__ __launch_bounds__(256)
void cast_x_k(const float4* __restrict__ in, ushort4* __restrict__ out, int n4)
{
    int i = blockIdx.x * 256 + threadIdx.x;
    if (i >= n4) return;
    float4 v = in[i];
    ushort4 o;
    o.x = f2bf(v.x); o.y = f2bf(v.y); o.z = f2bf(v.z); o.w = f2bf(v.w);
    out[i] = o;
}

// all weight preps in one launch:
//   [0, 2304*512)       in_proj pad+cast -> wip
//   [+, 1024*512)       w1 fold+cast     -> w1eb
//   [+, 512*1024)       out_proj cast    -> wopb
//   [+, 512*1024)       w2 cast          -> w2b
__global__ __launch_bounds__(256)
void prep_weights(const float* __restrict__ ipw, const float* __restrict__ w1,
                  const float* __restrict__ wop, const float* __restrict__ w2,
                  ushort* __restrict__ wip, ushort* __restrict__ w1eb,
                  ushort* __restrict__ wopb, ushort* __restrict__ w2b)
{
    int i4 = (blockIdx.x * 256 + threadIdx.x) * 4;
    if (i4 < NPAD * 512) {
        int row = i4 >> 9;
        ushort4 v;
        if (row < 2192) {
            float4 s = *(const float4*)(ipw + (size_t)i4);
            v.x = f2bf(s.x); v.y = f2bf(s.y); v.z = f2bf(s.z); v.w = f2bf(s.w);
        } else { v.x = v.y = v.z = v.w = 0; }
        *(ushort4*)(wip + i4) = v;
        return;
    }
    i4 -= NPAD * 512;
    if (i4 < 1024 * 512) {
        int j = i4 >> 9, d = i4 & 511;
        float4 a = *(const float4*)(w1 + (size_t)j * 1024 + d);
        float4 b = *(const float4*)(w1 + (size_t)j * 1024 + 512 + d);
        ushort4 v;
        v.x = f2bf(a.x + b.x); v.y = f2bf(a.y + b.y);
        v.z = f2bf(a.z + b.z); v.w = f2bf(a.w + b.w);
        *(ushort4*)(w1eb + i4) = v;
        return;
    }
    i4 -= 1024 * 512;
    if (i4 < 512 * 1024) {
        float4 s = *(const float4*)(wop + (size_t)i4);
        ushort4 v;
        v.x = f2bf(s.x); v.y = f2bf(s.y); v.z = f2bf(s.z); v.w = f2bf(s.w);
        *(ushort4*)(wopb + i4) = v;
        return;
    }
    i4 -= 512 * 1024;
    if (i4 < 512 * 1024) {
        float4 s = *(const float4*)(w2 + (size_t)i4);
        ushort4 v;
        v.x = f2bf(s.x); v.y = f2bf(s.y); v.z = f2bf(s.z); v.w = f2bf(s.w);
        *(ushort4*)(w2b + i4) = v;
    }
}

// ---------------------------------------------------------------------------
// seg_scan (dt fused): per chunk of 128 scan-steps,
//   v = raw_dt + dt_bias; dt = softplus(v); lda = dt * (-exp(A_log))
//   seg = inclusive cumsum(lda); alpha = exp(seg_last - seg)*dt; P = exp(seg_last)
// ---------------------------------------------------------------------------
__global__ __launch_bounds__(128)
void seg_scan(const ushort* __restrict__ raw, const float* __restrict__ dt_bias,
              const float* __restrict__ A_log, float* __restrict__ dtr,
              float* __restrict__ segb, float* __restrict__ alphab,
              float* __restrict__ Pb)
{
    __shared__ float s[128];
    const int tid = threadIdx.x;
    const int c = blockIdx.x, h = blockIdx.y, b = blockIdx.z;
    const int bh = b * 16 + h;
    const int r = c * QCH + tid;
    const size_t grow = (size_t)b * LSEQ + (LSEQ - 1 - r);
    const size_t idx = (size_t)bh * LSEQ + r;

    float v = bf2f(raw[grow * NPAD + 2176 + h]) + dt_bias[h];
    float dt = (v > 20.f) ? v : log1pf(expf(v));
    float Ah = -expf(A_log[h]);
    s[tid] = dt * Ah;
    __syncthreads();
#pragma unroll
    for (int off = 1; off < 128; off <<= 1) {
        float t = (tid >= off) ? s[tid - off] : 0.f;
        __syncthreads();
        s[tid] += t;
        __syncthreads();
    }
    float seg = s[tid];
    float last = s[127];
    dtr[idx] = dt;
    segb[idx] = seg;
    alphab[idx] = __expf(last - seg) * dt;
    if (tid == 127) Pb[bh * NCH + c] = __expf(last);
}

// ---------------------------------------------------------------------------
// Anti-causal depthwise conv + silu, vectorized: thread = (row, 8-ch group).
// 16B loads/stores. Splits output into xh [T,1024] and bc [T,128].
// ---------------------------------------------------------------------------
__global__ __launch_bounds__(256)
void conv_silu(const ushort* __restrict__ raw, const float* __restrict__ cw,
               const float* __restrict__ cb, ushort* __restrict__ xh,
               ushort* __restrict__ bc)
{
    const int idx = blockIdx.x * 256 + threadIdx.x;   // over TTOK*144
    if (idx >= TTOK * 144) return;
    const int row = idx / 144;
    const int g = idx - row * 144;
    const int c0 = g * 8;
    const int l = row & (LSEQ - 1);

    float acc[8];
    float4 wv[8];
#pragma unroll
    for (int e = 0; e < 8; ++e) {
        acc[e] = cb[c0 + e];
        wv[e] = *(const float4*)(cw + (c0 + e) * 4);
    }
    const float* wf = (const float*)wv;
#pragma unroll
    for (int k = 0; k < 4; ++k) {
        int ll = l + 3 - k;
        if (ll < LSEQ) {
            ushortx8 v = *(const ushortx8*)(raw + (size_t)(row + 3 - k) * NPAD + 1024 + c0);
#pragma unroll
            for (int e = 0; e < 8; ++e)
                acc[e] = fmaf(wf[e * 4 + k], bf2f(v[e]), acc[e]);
        }
    }
    ushortx8 o;
#pragma unroll
    for (int e = 0; e < 8; ++e) {
        float a = acc[e];
        a = a / (1.f + __expf(-a));
        o[e] = f2bf(a);
    }
    if (c0 < 1024) *(ushortx8*)(xh + (size_t)row * 1024 + c0) = o;
    else           *(ushortx8*)(bc + (size_t)row * 128 + (c0 - 1024)) = o;
}

// ---------------------------------------------------------------------------
// SSD pass A: per tile (c,h,b), chunk end-state
//   L[p,n] = sum_tau XT[p,tau] * (alpha(tau)*B[tau,n])
// ---------------------------------------------------------------------------
__global__ __launch_bounds__(256)
void ssd_states(const ushort* __restrict__ xh, const ushort* __restrict__ bc,
                const float* __restrict__ alphab, float* __restrict__ sbuf)
{
    __shared__ __align__(16) ushort XT[64 * 136];
    __shared__ __align__(16) ushort BpT[64 * 136];
    const int tid = threadIdx.x;
    const int w = tid >> 6, lane = tid & 63;
    const int lm = lane & 15, quad = lane >> 4;
    const int c = blockIdx.x, h = blockIdx.y, b = blockIdx.z;
    const int bh = b * 16 + h;
    const size_t abase = (size_t)bh * LSEQ + c * QCH;

#pragma unroll
    for (int it = 0; it < 8; ++it) {
        int idx = it * 256 + tid;
        int tau = idx >> 4, e4 = (idx & 15) * 4;
        size_t grow = (size_t)b * LSEQ + (LSEQ - 1 - (c * QCH + tau));
        ushort4 xv = *(const ushort4*)(xh + grow * 1024 + h * 64 + e4);
        XT[(e4 + 0) * 136 + tau] = xv.x;
        XT[(e4 + 1) * 136 + tau] = xv.y;
        XT[(e4 + 2) * 136 + tau] = xv.z;
        XT[(e4 + 3) * 136 + tau] = xv.w;
        float al = alphab[abase + tau];
        ushort4 bv = *(const ushort4*)(bc + grow * 128 + e4);
        BpT[(e4 + 0) * 136 + tau] = f2bf(bf2f(bv.x) * al);
        BpT[(e4 + 1) * 136 + tau] = f2bf(bf2f(bv.y) * al);
        BpT[(e4 + 2) * 136 + tau] = f2bf(bf2f(bv.z) * al);
        BpT[(e4 + 3) * 136 + tau] = f2bf(bf2f(bv.w) * al);
    }
    __syncthreads();

    floatx4 L[4];
#pragma unroll
    for (int j = 0; j < 4; ++j) L[j] = (floatx4){0.f, 0.f, 0.f, 0.f};
#pragma unroll
    for (int kc = 0; kc < 4; ++kc) {
        short8 a = *(const short8*)(XT + (w * 16 + lm) * 136 + kc * 32 + quad * 8);
#pragma unroll
        for (int jn = 0; jn < 4; ++jn) {
            short8 bf = *(const short8*)(BpT + (jn * 16 + lm) * 136 + kc * 32 + quad * 8);
            L[jn] = __builtin_amdgcn_mfma_f32_16x16x32_bf16(a, bf, L[jn], 0, 0, 0);
        }
    }
    float* Sp = sbuf + ((size_t)bh * NCH + c) * 4096;
#pragma unroll
    for (int jn = 0; jn < 4; ++jn)
#pragma unroll
        for (int r = 0; r < 4; ++r) {
            int p = w * 16 + quad * 4 + r;
            Sp[p * 64 + jn * 16 + lm] = L[jn][r];
        }
}

// ---------------------------------------------------------------------------
// Combine: sequential over chunks in scan (r) order, software-prefetched.
// ---------------------------------------------------------------------------
__global__ __launch_bounds__(256)
void scan_combine(float* __restrict__ sbuf, const float* __restrict__ Pb)
{
    const int tid = threadIdx.x;
    const int h = blockIdx.y, b = blockIdx.z;
    const int bh = b * 16 + h;
    const int off = tid * 16;
    float carry[16];
#pragma unroll
    for (int j = 0; j < 16; ++j) carry[j] = 0.f;

    float* sp0 = sbuf + (size_t)bh * NCH * 4096 + off;
    float4 n0 = *(const float4*)(sp0 + 0);
    float4 n1 = *(const float4*)(sp0 + 4);
    float4 n2 = *(const float4*)(sp0 + 8);
    float4 n3 = *(const float4*)(sp0 + 12);
    float Pn = Pb[bh * NCH];

    for (int c = 0; c < NCH; ++c) {
        float4 l0 = n0, l1 = n1, l2 = n2, l3 = n3;
        float P = Pn;
        if (c + 1 < NCH) {
            const float* spn = sp0 + (size_t)(c + 1) * 4096;
            n0 = *(const float4*)(spn + 0);
            n1 = *(const float4*)(spn + 4);
            n2 = *(const float4*)(spn + 8);
            n3 = *(const float4*)(spn + 12);
            Pn = Pb[bh * NCH + c + 1];
        }
        float* sp = sp0 + (size_t)c * 4096;
        *(float4*)(sp + 0)  = make_float4(carry[0],  carry[1],  carry[2],  carry[3]);
        *(float4*)(sp + 4)  = make_float4(carry[4],  carry[5],  carry[6],  carry[7]);
        *(float4*)(sp + 8)  = make_float4(carry[8],  carry[9],  carry[10], carry[11]);
        *(float4*)(sp + 12) = make_float4(carry[12], carry[13], carry[14], carry[15]);
        float lv[16] = {l0.x, l0.y, l0.z, l0.w, l1.x, l1.y, l1.z, l1.w,
                        l2.x, l2.y, l2.z, l2.w, l3.x, l3.y, l3.z, l3.w};
#pragma unroll
        for (int j = 0; j < 16; ++j) carry[j] = fmaf(carry[j], P, lv[j]);
    }
}

// ---------------------------------------------------------------------------
// SSD pass C: Y = [M o (C B^T)] X + diag(exp(seg)) C h_start^T, D on diagonal,
// z-gate fused, writes gated bf16.
// ---------------------------------------------------------------------------
__global__ __launch_bounds__(256)
void ssd_y(const ushort* __restrict__ xh, const ushort* __restrict__ bc,
           const float* __restrict__ segb, const float* __restrict__ dtb_,
           const float* __restrict__ Dvec, const float* __restrict__ sbuf,
           const ushort* __restrict__ zb, ushort* __restrict__ gz)
{
    __shared__ __align__(16) char smem[72192];
    ushort* Ct  = (ushort*)smem;            // [128][72]
    ushort* XT  = (ushort*)(smem + 18432);  // [64][136]
    ushort* Bt  = (ushort*)(smem + 35840);  // [128][72]  (dead after GEMM1)
    ushort* Wl  = (ushort*)(smem + 35840);  // [128][136] (overlaps Bt)
    float* segl = (float*)(smem + 70656);   // [128]
    float* dtl  = (float*)(smem + 71168);   // [128]

    const int tid = threadIdx.x;
    const int w = tid >> 6, lane = tid & 63;
    const int lm = lane & 15, quad = lane >> 4;
    const int c = blockIdx.x, h = blockIdx.y, b = blockIdx.z;
    const int bh = b * 16 + h;
    const size_t abase = (size_t)bh * LSEQ + c * QCH;

    if (tid < 128) {
        segl[tid] = segb[abase + tid];
        dtl[tid]  = dtb_[abase + tid];
    }
#pragma unroll
    for (int it = 0; it < 8; ++it) {
        int idx = it * 256 + tid;
        int tau = idx >> 4, e4 = (idx & 15) * 4;
        size_t grow = (size_t)b * LSEQ + (LSEQ - 1 - (c * QCH + tau));
        ushort4 bv = *(const ushort4*)(bc + grow * 128 + e4);
        ushort4 cv = *(const ushort4*)(bc + grow * 128 + 64 + e4);
        *(ushort4*)(Bt + tau * 72 + e4) = bv;
        *(ushort4*)(Ct + tau * 72 + e4) = cv;
        ushort4 xv = *(const ushort4*)(xh + grow * 1024 + h * 64 + e4);
        XT[(e4 + 0) * 136 + tau] = xv.x;
        XT[(e4 + 1) * 136 + tau] = xv.y;
        XT[(e4 + 2) * 136 + tau] = xv.z;
        XT[(e4 + 3) * 136 + tau] = xv.w;
    }
    __syncthreads();

    // GEMM1: G = C . B^T ; wave w owns rows [w*32,+32)
    floatx4 G[2][8];
#pragma unroll
    for (int i = 0; i < 2; ++i)
#pragma unroll
        for (int j = 0; j < 8; ++j) G[i][j] = (floatx4){0.f, 0.f, 0.f, 0.f};
#pragma unroll
    for (int kc = 0; kc < 2; ++kc) {
        short8 a[2];
#pragma unroll
        for (int i = 0; i < 2; ++i)
            a[i] = *(const short8*)(Ct + (w * 32 + i * 16 + lm) * 72 + kc * 32 + quad * 8);
#pragma unroll
        for (int jn = 0; jn < 8; ++jn) {
            short8 bf = *(const short8*)(Bt + (jn * 16 + lm) * 72 + kc * 32 + quad * 8);
#pragma unroll
            for (int i = 0; i < 2; ++i)
                G[i][jn] = __builtin_amdgcn_mfma_f32_16x16x32_bf16(a[i], bf, G[i][jn], 0, 0, 0);
        }
    }
    __syncthreads();   // everyone done reading Bt before Wl overwrites it

    const float Dh = Dvec[h];
#pragma unroll
    for (int i = 0; i < 2; ++i) {
        const int taub = w * 32 + i * 16;
#pragma unroll
        for (int jn = 0; jn < 8; ++jn) {
            const int sigma = jn * 16 + lm;
            const float dts = dtl[sigma];
            const float segs = segl[sigma];
#pragma unroll
            for (int r = 0; r < 4; ++r) {
                const int tau = taub + quad * 4 + r;
                float g = G[i][jn][r];
                float wv;
                if (sigma < tau)       wv = dts * g * __expf(segl[tau] - segs);
                else if (sigma == tau) wv = dts * g + Dh;
                else                   wv = 0.f;
                Wl[tau * 136 + sigma] = f2bf(wv);
            }
        }
    }
    // no barrier needed: each wave reads back only its own W rows

    // GEMM2: Y = W.X + (exp(seg) C).H^T
    floatx4 Y[2][4];
#pragma unroll
    for (int i = 0; i < 2; ++i)
#pragma unroll
        for (int j = 0; j < 4; ++j) Y[i][j] = (floatx4){0.f, 0.f, 0.f, 0.f};
#pragma unroll
    for (int kc = 0; kc < 4; ++kc) {
        short8 a[2];
#pragma unroll
        for (int i = 0; i < 2; ++i)
            a[i] = *(const short8*)(Wl + (w * 32 + i * 16 + lm) * 136 + kc * 32 + quad * 8);
#pragma unroll
        for (int jn = 0; jn < 4; ++jn) {
            short8 bf = *(const short8*)(XT + (jn * 16 + lm) * 136 + kc * 32 + quad * 8);
#pragma unroll
            for (int i = 0; i < 2; ++i)
                Y[i][jn] = __builtin_amdgcn_mfma_f32_16x16x32_bf16(a[i], bf, Y[i][jn], 0, 0, 0);
        }
    }
    const float* Hp = sbuf + ((size_t)bh * NCH + c) * 4096;
#pragma unroll
    for (int kc = 0; kc < 2; ++kc) {
        short8 a[2];
#pragma unroll
        for (int i = 0; i < 2; ++i) {
            const int row = w * 32 + i * 16 + lm;
            const float es = __expf(segl[row]);
            short8 craw = *(const short8*)(Ct + row * 72 + kc * 32 + quad * 8);
#pragma unroll
            for (int e = 0; e < 8; ++e)
                a[i][e] = (short)f2bf(bf2f((ushort)craw[e]) * es);
        }
#pragma unroll
        for (int jn = 0; jn < 4; ++jn) {
            const float* hp = Hp + (jn * 16 + lm) * 64 + kc * 32 + quad * 8;
            float4 h0 = *(const float4*)(hp);
            float4 h1 = *(const float4*)(hp + 4);
            short8 bf;
            bf[0] = (short)f2bf(h0.x); bf[1] = (short)f2bf(h0.y);
            bf[2] = (short)f2bf(h0.z); bf[3] = (short)f2bf(h0.w);
            bf[4] = (short)f2bf(h1.x); bf[5] = (short)f2bf(h1.y);
            bf[6] = (short)f2bf(h1.z); bf[7] = (short)f2bf(h1.w);
#pragma unroll
            for (int i = 0; i < 2; ++i)
                Y[i][jn] = __builtin_amdgcn_mfma_f32_16x16x32_bf16(a[i], bf, Y[i][jn], 0, 0, 0);
        }
    }

    // epilogue: z-gate, store gated bf16
#pragma unroll
    for (int i = 0; i < 2; ++i) {
#pragma unroll
        for (int r = 0; r < 4; ++r) {
            const int tau = w * 32 + i * 16 + quad * 4 + r;
            const size_t grow = (size_t)b * LSEQ + (LSEQ - 1 - (c * QCH + tau));
#pragma unroll
            for (int jn = 0; jn < 4; ++jn) {
                const int col = h * 64 + jn * 16 + lm;
                float yv = Y[i][jn][r];
                float zv = bf2f(zb[grow * NPAD + col]);
                float gv = yv * (zv / (1.f + __expf(-zv)));
                gz[grow * 1024 + col] = f2bf(gv);
            }
        }
    }
}

// ---------------------------------------------------------------------------
// RMS-norm over 1024 of gated values (bf16 in/out)
// ---------------------------------------------------------------------------
__global__ __launch_bounds__(256)
void rms_k(const ushort* __restrict__ gz, const float* __restrict__ rw,
           ushort* __restrict__ out)
{
    const int row = blockIdx.x;
    const int tid = threadIdx.x;
    float g[4];
    float ss = 0.f;
#pragma unroll
    for (int i = 0; i < 4; ++i) {
        int c = i * 256 + tid;
        float gv = bf2f(gz[(size_t)row * 1024 + c]);
        g[i] = gv;
        ss += gv * gv;
    }
#pragma unroll
    for (int off = 32; off > 0; off >>= 1) ss += __shfl_xor(ss, off);
    __shared__ float red[4];
    if ((tid & 63) == 0) red[tid >> 6] = ss;
    __syncthreads();
    ss = red[0] + red[1] + red[2] + red[3];
    const float inv = rsqrtf(ss * (1.f / 1024.f) + 1e-5f);
#pragma unroll
    for (int i = 0; i < 4; ++i) {
        int c = i * 256 + tid;
        out[(size_t)row * 1024 + c] = f2bf(g[i] * inv * rw[c]);
    }
}

// ---------------------------------------------------------------------------
// LayerNorm over 512, fp32 in, bf16 out
// ---------------------------------------------------------------------------
__global__ __launch_bounds__(256)
void layernorm_k(const float* __restrict__ x, const float* __restrict__ gg,
                 const float* __restrict__ bb, ushort* __restrict__ out)
{
    const int row = blockIdx.x;
    const int tid = threadIdx.x;
    float x0 = x[(size_t)row * 512 + tid];
    float x1 = x[(size_t)row * 512 + 256 + tid];
    float s = x0 + x1, ss = x0 * x0 + x1 * x1;
#pragma unroll
    for (int off = 32; off > 0; off >>= 1) {
        s += __shfl_xor(s, off);
        ss += __shfl_xor(ss, off);
    }
    __shared__ float rs[4], rss[4];
    if ((tid & 63) == 0) { rs[tid >> 6] = s; rss[tid >> 6] = ss; }
    __syncthreads();
    s = rs[0] + rs[1] + rs[2] + rs[3];
    ss = rss[0] + rss[1] + rss[2] + rss[3];
    const float mean = s * (1.f / 512.f);
    const float var = ss * (1.f / 512.f) - mean * mean;
    const float inv = rsqrtf(var + 1e-5f);
    out[(size_t)row * 512 + tid]       = f2bf((x0 - mean) * inv * gg[tid] + bb[tid]);
    out[(size_t)row * 512 + 256 + tid] = f2bf((x1 - mean) * inv * gg[256 + tid] + bb[256 + tid]);
}

// ---------------------------------------------------------------------------
extern "C" void kernel_launch(void* const* d_in, const int* in_sizes, int n_in,
                              void* d_out, int out_size, void* d_ws, size_t ws_size,
                              hipStream_t stream)
{
    const float* x         = (const float*)d_in[0];
    const float* in_proj_w = (const float*)d_in[1];   // (2192, 512)
    const float* conv_w    = (const float*)d_in[2];   // (1152, 4)
    const float* conv_b    = (const float*)d_in[3];
    const float* dt_bias   = (const float*)d_in[4];   // (16,)
    const float* A_log     = (const float*)d_in[5];
    const float* Dv        = (const float*)d_in[6];
    const float* rms_w     = (const float*)d_in[7];
    const float* out_proj_w= (const float*)d_in[8];   // (512, 1024)
    const float* ln_g      = (const float*)d_in[9];
    const float* ln_b      = (const float*)d_in[10];
    const float* w1        = (const float*)d_in[11];  // (1024, 1024)
    const float* b1        = (const float*)d_in[12];
    const float* w2        = (const float*)d_in[13];  // (512, 1024)
    const float* b2        = (const float*)d_in[14];
    float* out = (float*)d_out;
    char* base = (char*)d_ws;

    // workspace layout (byte offsets), liveness-safe reuse:
    ushort* g1out = (ushort*)(base);                   // [T,2304] bf16   75.5 MB
    ushort* xh_b  = (ushort*)(base + 75497472);        // [T,1024] bf16   33.5 MB
    ushort* bc_b  = (ushort*)(base + 109051904);       // [T,128]  bf16    4.2 MB
    ushort* gz    = (ushort*)(base + 113246208);       // [T,1024] bf16   33.5 MB
    ushort* xbf   = (ushort*)(base + 113246208);       // [T,512] bf16 (dead before gz)
    float*  dtr   = (float*) (base + 146800640);       // [64][4096]       1 MB
    float*  segb  = (float*) (base + 148897792);       // [64][4096]       1 MB
    float*  alphab= (float*) (base + 149946368);       // [64][4096]       1 MB
    ushort* wip   = (ushort*)(base + 150994944);       // [2304,512] bf16
    ushort* w1eb  = (ushort*)(base + 153354240);       // [1024,512] bf16
    ushort* wopb  = (ushort*)(base + 154402816);       // [512,1024] bf16
    ushort* w2b   = (ushort*)(base + 155451392);       // [512,1024] bf16
    float*  Pbuf  = (float*) (base + 156499968);       // [64*32]
    // post-scan reuse:
    ushort* vg  = xh_b;                                // [T,1024] bf16 (xh dead)
    float*  y2  = (float*)base;                        // [T,512] f32 (g1out dead)
    ushort* yln = (ushort*)(base + 33554432);          // [T,512] bf16
    ushort* h1  = gz;                                  // [T,1024] bf16 (gz dead)
    // chunk states: 64 tiles/seq-head x 4096 f32 == out_size; d_out dead until MLP2
    float* sbuf = out;

    // ---- casts ----
    cast_x_k<<<(TTOK * 512 / 4 + 255) / 256, 256, 0, stream>>>(
        (const float4*)x, (ushort4*)xbf, TTOK * 512 / 4);
    prep_weights<<<((NPAD * 512 + 1024 * 512 + 2 * 512 * 1024) / 4 + 255) / 256, 256, 0, stream>>>(
        in_proj_w, w1, out_proj_w, w2, wip, w1eb, wopb, w2b);

    // ---- in_proj ----
    gemm_mfma<0, ushort><<<dim3(NPAD / 128, TTOK / 128), 256, 0, stream>>>(
        xbf, wip, nullptr, g1out, TTOK, NPAD, 512);

    seg_scan<<<dim3(NCH, 16, 4), 128, 0, stream>>>(g1out, dt_bias, A_log, dtr, segb, alphab, Pbuf);
    conv_silu<<<(TTOK * 144 + 255) / 256, 256, 0, stream>>>(g1out, conv_w, conv_b, xh_b, bc_b);

    // ---- SSD chunked scan ----
    ssd_states  <<<dim3(NCH, 16, 4), 256, 0, stream>>>(xh_b, bc_b, alphab, sbuf);
    scan_combine<<<dim3(1, 16, 4),   256, 0, stream>>>(sbuf, Pbuf);
    ssd_y       <<<dim3(NCH, 16, 4), 256, 0, stream>>>(xh_b, bc_b, segb, dtr, Dv, sbuf, g1out, gz);

    // ---- norm + projections + MLP ----
    rms_k<<<TTOK, 256, 0, stream>>>(gz, rms_w, vg);
    gemm_mfma<0, float><<<dim3(512 / 128, TTOK / 128), 256, 0, stream>>>(
        vg, wopb, nullptr, y2, TTOK, 512, 1024);
    layernorm_k<<<TTOK, 256, 0, stream>>>(y2, ln_g, ln_b, yln);
    gemm_mfma<1, ushort><<<dim3(1024 / 128, TTOK / 128), 256, 0, stream>>>(
        yln, w1eb, b1, h1, TTOK, 1024, 512);
    gemm_mfma<0, float><<<dim3(512 / 128, TTOK / 128), 256, 0, stream>>>(
        h1, w2b, b2, out, TTOK, 512, 1024);
}